// Round 3
// baseline (381.327 us; speedup 1.0000x reference)
//
#include <hip/hip_runtime.h>

typedef unsigned short u16;
using bf16x8 = __attribute__((ext_vector_type(8))) __bf16;
using f32x4  = __attribute__((ext_vector_type(4))) float;
using u32x2  = __attribute__((ext_vector_type(2))) unsigned;
using u32x4  = __attribute__((ext_vector_type(4))) unsigned;

#define AS1 __attribute__((address_space(1)))
#define AS3 __attribute__((address_space(3)))

__device__ __forceinline__ void glds16(const u16* g, u16* l) {
  __builtin_amdgcn_global_load_lds((AS1 void*)const_cast<u16*>(g), (AS3 void*)l, 16, 0, 0);
}

__device__ __forceinline__ u16 f2bf(float f) {
  unsigned u = __float_as_uint(f);
  u += 0x7FFFu + ((u >> 16) & 1u);
  return (u16)(u >> 16);
}
__device__ __forceinline__ ushort4 cvt4(float4 v) {
  return make_ushort4(f2bf(v.x), f2bf(v.y), f2bf(v.z), f2bf(v.w));
}

__device__ __forceinline__ unsigned cvt_pk_bf16(float lo, float hi) {
  unsigned r;
  asm("v_cvt_pk_bf16_f32 %0, %1, %2" : "=v"(r) : "v"(lo), "v"(hi));
  return r;
}

// full quad exchange via permlane32_swap + permlane16_swap (see r0 derivation):
// yields PV A-frag dword pairs from per-lane packed P values.
__device__ __forceinline__ void quad_swap(unsigned& x, unsigned& y) {
  u32x2 a = __builtin_amdgcn_permlane32_swap(x, y, false, false);
  u32x2 b = __builtin_amdgcn_permlane16_swap(a[0], a[1], false, false);
  x = b[0];
  y = b[1];
}

// ---------------- one-shot fp32 -> bf16 conversion ----------------
__global__ __launch_bounds__(256) void cvt_kernel(const float4* __restrict__ hs,
    const float4* __restrict__ wq, const float4* __restrict__ wk,
    const float4* __restrict__ wv, const float4* __restrict__ wo, u16* __restrict__ dst) {
  const long stride = (long)gridDim.x * blockDim.x;
  for (long i = (long)blockIdx.x * blockDim.x + threadIdx.x; i < 3558400; i += stride) {
    const float4* src; long rel; u16* d;
    if (i < 1920000)      { src = hs; rel = i;           d = dst; }
    else if (i < 2329600) { src = wq; rel = i - 1920000; d = dst + 7680000; }
    else if (i < 2739200) { src = wk; rel = i - 2329600; d = dst + 9318400; }
    else if (i < 3148800) { src = wv; rel = i - 2739200; d = dst + 10956800; }
    else                  { src = wo; rel = i - 3148800; d = dst + 12595200; }
    *(ushort4*)(d + rel * 4) = cvt4(src[rel]);
  }
}

// ---------------- bf16 GEMM, 2-phase double-buffered global_load_lds ----------------
// T3-minimum schedule: issue next K-tile's async loads into buf^1, compute buf, one
// barrier/iter (drains vmcnt before s_barrier -> prefetch latency hidden by compute).
// As/Bs are [2][128*32] u16 (16KB each). m0/n0 from callers' XCD-banded remap.
template <int MODE, typename OT>
__device__ __forceinline__ void gemm_bf(const u16* __restrict__ A, const u16* __restrict__ W,
                                        const float* __restrict__ bias, OT* __restrict__ out,
                                        float scale, int M, u16* As, u16* Bs,
                                        int m0, int n0) {
  constexpr int K = 1280;
  constexpr int NIT = K / 32;                   // 40 K-iterations
  const int tid = threadIdx.x, wid = tid >> 6, lane = tid & 63;
  const int lm = lane & 15, quad = lane >> 4;
  const int wm = (wid >> 1) * 64, wn = (wid & 1) * 64;

  f32x4 acc[4][4] = {};

  const int ch0 = wid * 64 + lane, ch1 = 256 + ch0;
  int rA0 = m0 + (ch0 >> 2); rA0 = rA0 < M ? rA0 : M - 1;
  int rA1 = m0 + (ch1 >> 2); rA1 = rA1 < M ? rA1 : M - 1;
  const int kc0 = (ch0 & 3) * 8, kc1 = (ch1 & 3) * 8;
  const u16* a0 = A + (size_t)rA0 * K + kc0;
  const u16* a1 = A + (size_t)rA1 * K + kc1;
  const u16* w0 = W + (size_t)(n0 + (ch0 >> 2)) * K + kc0;
  const u16* w1 = W + (size_t)(n0 + (ch1 >> 2)) * K + kc1;
  u16* lA = As + wid * 512;                     // + bi*4096 selects buffer
  u16* lB = Bs + wid * 512;

  auto stage = [&](int kt, int bi) {
    glds16(a0 + kt, lA + bi * 4096);
    glds16(a1 + kt, lA + bi * 4096 + 2048);
    glds16(w0 + kt, lB + bi * 4096);
    glds16(w1 + kt, lB + bi * 4096 + 2048);
  };

  stage(0, 0);
  __syncthreads();                              // buf0 ready (vmcnt drained pre-barrier)

  for (int it = 0; it < NIT; ++it) {
    const int cur = it & 1;
    if (it + 1 < NIT) stage((it + 1) * 32, cur ^ 1);   // async into other buffer
    const u16* Ab = As + cur * 4096;
    const u16* Bb = Bs + cur * 4096;
    bf16x8 af[4], bfr[4];
#pragma unroll
    for (int i = 0; i < 4; ++i) af[i] = *(const bf16x8*)(Ab + (wm + i * 16 + lm) * 32 + quad * 8);
#pragma unroll
    for (int j = 0; j < 4; ++j) bfr[j] = *(const bf16x8*)(Bb + (wn + j * 16 + lm) * 32 + quad * 8);
#pragma unroll
    for (int i = 0; i < 4; ++i)
#pragma unroll
      for (int j = 0; j < 4; ++j)
        acc[i][j] = __builtin_amdgcn_mfma_f32_16x16x32_bf16(af[i], bfr[j], acc[i][j], 0, 0, 0);
    __syncthreads();                            // next buffer ready; cur safe to overwrite
  }

#pragma unroll
  for (int j = 0; j < 4; ++j) {
    const int col = n0 + wn + j * 16 + lm;
    const float bb = bias ? bias[col] : 0.0f;
    const int hh = col >> 6, dd = col & 63;
#pragma unroll
    for (int i = 0; i < 4; ++i) {
      const int row0 = m0 + wm + i * 16 + quad * 4;
#pragma unroll
      for (int r = 0; r < 4; ++r) {
        const int row = row0 + r;
        if (row < M) {
          const float v = (acc[i][j][r] + bb) * scale;
          if (MODE == 0) {
            out[(size_t)row * 1280 + col] = (OT)v;
          } else {
            const int bidx = row / 1500, s = row - bidx * 1500;
            if (MODE == 1)
              out[((size_t)(bidx * 20 + hh) * 1500 + s) * 64 + dd] = (OT)f2bf(v);
            else
              out[((size_t)(bidx * 20 + hh) * 64 + dd) * 1504 + s] = (OT)f2bf(v);
          }
        }
      }
    }
  }
}

// XCD-banded remap (bijective, m204-style): each XCD owns a contiguous band of
// A-row panels (6,6,6,6,6,6,6,5 over 47) -> per-XCD A working set 1.9MB (L2-fit).
// x innermost so each B panel is consumed while L2-hot.
__global__ __launch_bounds__(256) void qkv_kernel(const u16* __restrict__ hs,
    const u16* __restrict__ Wq, const float* __restrict__ bq, const u16* __restrict__ Wk,
    const u16* __restrict__ Wv, const float* __restrict__ bv,
    u16* __restrict__ q_ws, u16* __restrict__ k_ws, u16* __restrict__ vt_ws, int M) {
  __shared__ __align__(16) u16 As[2 * 128 * 32];
  __shared__ __align__(16) u16 Bs[2 * 128 * 32];
  const int n = blockIdx.x;                     // grid = 1440 (8 XCD * 180)
  const int xcd = n & 7, j = n >> 3;            // j in [0,180)
  const int x = xcd * 6 + (j % 6);
  if (x >= 47) return;                          // block-uniform: safe before barriers
  const int yz = j / 6;                         // [0,30)
  const int y = yz % 10, z = yz / 10;
  const int m0 = x * 128, n0 = y * 128;
  if (z == 0)
    gemm_bf<1, u16>(hs, Wq, bq, q_ws, 0.18033688f, M, As, Bs, m0, n0);  // 0.125*log2(e)
  else if (z == 1)
    gemm_bf<1, u16>(hs, Wk, nullptr, k_ws, 1.0f, M, As, Bs, m0, n0);
  else
    gemm_bf<2, u16>(hs, Wv, bv, vt_ws, 1.0f, M, As, Bs, m0, n0);
}

__global__ __launch_bounds__(256) void out_kernel(const u16* __restrict__ attn,
    const u16* __restrict__ Wo, const float* __restrict__ bo, float* __restrict__ out, int M) {
  __shared__ __align__(16) u16 As[2 * 128 * 32];
  __shared__ __align__(16) u16 Bs[2 * 128 * 32];
  const int n = blockIdx.x;                     // grid = 480 (8 XCD * 60)
  const int xcd = n & 7, j = n >> 3;            // j in [0,60)
  const int x = xcd * 6 + (j % 6);
  if (x >= 47) return;
  const int y = j / 6;                          // [0,10)
  gemm_bf<0, float>(attn, Wo, bo, out, 1.0f, M, As, Bs, x * 128, y * 128);
}

// ---------------- Flash attention: swapped QK^T, in-register softmax/P ----------------
// Q,K: [b,h,1500,64] bf16 (Q pre-scaled by 0.125*log2e); Vt: [b,h,64,1504] bf16.
// 4 waves; wave owns 32 q-rows as 2 groups of 16. S^T = mfma(K,Q): each lane owns one
// q-row (lm) with kpos = t*16+quad*4+r -> per-lane scalar m/l, 2-shfl reductions.
// P -> bf16 A-frags fully in-register: cvt_pk pairs + permlane32/16_swap quad exchange.
// K/V staged via global_load_lds (pre-swizzled source, linear LDS dest), dbuf, 1 barrier/iter.
__global__ __launch_bounds__(256, 4) void attn_kernel(const u16* __restrict__ Qm,
    const u16* __restrict__ Km, const u16* __restrict__ Vtm, u16* __restrict__ Out) {
  const int qt = blockIdx.x, h = blockIdx.y, b = blockIdx.z;
  const int bh = b * 20 + h;
  const int tid = threadIdx.x, wid = tid >> 6, lane = tid & 63;
  const int lm = lane & 15, quad = lane >> 4;

  __shared__ __align__(16) u16 Ks[2][64 * 64];    // [kpos][d], XOR-chunk swizzled
  __shared__ __align__(16) u16 Vts[2][64 * 64];   // [d][kpos], swizzled

  const u16* Qb = Qm + (size_t)bh * (1500 * 64);
  const u16* Kb = Km + (size_t)bh * (1500 * 64);
  const u16* Vb = Vtm + (size_t)bh * (64 * 1504);

  bf16x8 qf[2][2];
#pragma unroll
  for (int g = 0; g < 2; ++g) {
    int qrow = qt * 128 + wid * 32 + g * 16 + lm;
    if (qrow > 1499) qrow = 1499;                 // dup rows masked at store
    qf[g][0] = *(const bf16x8*)(Qb + (size_t)qrow * 64 + quad * 8);
    qf[g][1] = *(const bf16x8*)(Qb + (size_t)qrow * 64 + 32 + quad * 8);
  }

  // staging geometry: thread (rr, cc) stages 16B chunks; swizzle on the GLOBAL side,
  // LDS dest is linear (wave-uniform base + lane*16B) as global_load_lds requires.
  const int rr = tid >> 3, cc = tid & 7;
  const int s0 = (cc ^ (rr & 7)) * 8;             // (rr+32)&7 == rr&7

  auto stage = [&](int kt, int bi) {
    int kr0 = kt + rr;      if (kr0 > 1499) kr0 = 1499;
    int kr1 = kt + rr + 32; if (kr1 > 1499) kr1 = 1499;
    int vcol = kt + s0;     if (vcol > 1496) vcol = 1496;   // keep V reads in-bounds/finite
    u16* lk = &Ks[bi][0] + wid * 512;
    u16* lv = &Vts[bi][0] + wid * 512;
    glds16(Kb + (size_t)kr0 * 64 + s0, lk);
    glds16(Kb + (size_t)kr1 * 64 + s0, lk + 2048);
    glds16(Vb + (size_t)rr * 1504 + vcol, lv);
    glds16(Vb + (size_t)(rr + 32) * 1504 + vcol, lv + 2048);
  };

  stage(0, 0);
  __syncthreads();

  float m_s[2] = {-1e30f, -1e30f};
  float l_s[2] = {0.f, 0.f};
  f32x4 o_acc[2][4] = {};

  for (int it = 0; it < 24; ++it) {
    const int cur = it & 1;
    if (it + 1 < 24) stage((it + 1) * 64, cur ^ 1);   // async into other buffer

    // S^T = K Q^T : st[g][t] lane holds q-row lm, kpos = t*16 + quad*4 + r
    f32x4 st[2][4] = {};
    __builtin_amdgcn_s_setprio(1);
#pragma unroll
    for (int kk = 0; kk < 2; ++kk) {
#pragma unroll
      for (int t = 0; t < 4; ++t) {
        const bf16x8 kf = *(const bf16x8*)(&Ks[cur][(t * 16 + lm) * 64 + (((kk * 4 + quad) ^ (lm & 7)) * 8)]);
        st[0][t] = __builtin_amdgcn_mfma_f32_16x16x32_bf16(kf, qf[0][kk], st[0][t], 0, 0, 0);
        st[1][t] = __builtin_amdgcn_mfma_f32_16x16x32_bf16(kf, qf[1][kk], st[1][t], 0, 0, 0);
      }
    }
    __builtin_amdgcn_s_setprio(0);
    if (it == 23) {                               // ragged tile: kpos = 1472 + t*16+quad*4+r
#pragma unroll
      for (int t = 0; t < 4; ++t)
#pragma unroll
        for (int r = 0; r < 4; ++r)
          if (t * 16 + quad * 4 + r >= 28) { st[0][t][r] = -1e30f; st[1][t][r] = -1e30f; }
    }

    float alpha_s[2];
    bf16x8 pf[2][2];
#pragma unroll
    for (int g = 0; g < 2; ++g) {
      // row max: in-lane tree over 16 vals + 2 cross-quad shuffles
      float a0 = fmaxf(fmaxf(st[g][0][0], st[g][0][1]), fmaxf(st[g][0][2], st[g][0][3]));
      float a1 = fmaxf(fmaxf(st[g][1][0], st[g][1][1]), fmaxf(st[g][1][2], st[g][1][3]));
      float a2 = fmaxf(fmaxf(st[g][2][0], st[g][2][1]), fmaxf(st[g][2][2], st[g][2][3]));
      float a3 = fmaxf(fmaxf(st[g][3][0], st[g][3][1]), fmaxf(st[g][3][2], st[g][3][3]));
      float rm = fmaxf(fmaxf(a0, a1), fmaxf(a2, a3));
      rm = fmaxf(rm, __shfl_xor(rm, 16));
      rm = fmaxf(rm, __shfl_xor(rm, 32));
      const float mn = fmaxf(m_s[g], rm);
      const float al = exp2f(m_s[g] - mn);
      m_s[g] = mn;
      alpha_s[g] = al;

      float rs = 0.f;
      unsigned A[4], B[4];
#pragma unroll
      for (int t = 0; t < 4; ++t) {
        const float p0 = exp2f(st[g][t][0] - mn);
        const float p1 = exp2f(st[g][t][1] - mn);
        const float p2 = exp2f(st[g][t][2] - mn);
        const float p3 = exp2f(st[g][t][3] - mn);
        rs += (p0 + p1) + (p2 + p3);
        A[t] = cvt_pk_bf16(p0, p1);
        B[t] = cvt_pk_bf16(p2, p3);
      }
      rs += __shfl_xor(rs, 16);
      rs += __shfl_xor(rs, 32);
      l_s[g] = l_s[g] * al + rs;

      // redistribute P into PV A-frag layout: lane ends with P[lm][kk*32+quad*8 .. +7]
#pragma unroll
      for (int kk = 0; kk < 2; ++kk) {
        unsigned x0 = A[2 * kk], x1 = A[2 * kk + 1];
        quad_swap(x0, x1);                        // -> dwords 0 (k+0,1) and 2 (k+4,5)
        unsigned y0 = B[2 * kk], y1 = B[2 * kk + 1];
        quad_swap(y0, y1);                        // -> dwords 1 (k+2,3) and 3 (k+6,7)
        u32x4 w; w[0] = x0; w[1] = y0; w[2] = x1; w[3] = y1;
        pf[g][kk] = __builtin_bit_cast(bf16x8, w);
      }
    }

    // rescale O in accumulator layout (q-row = quad*4+r): pull alpha from lane lm=q-row
#pragma unroll
    for (int g = 0; g < 2; ++g)
#pragma unroll
      for (int r = 0; r < 4; ++r) {
        const float ao = __shfl(alpha_s[g], quad * 4 + r);
#pragma unroll
        for (int t = 0; t < 4; ++t) o_acc[g][t][r] *= ao;
      }

    // O += P V
    __builtin_amdgcn_s_setprio(1);
#pragma unroll
    for (int kk = 0; kk < 2; ++kk) {
#pragma unroll
      for (int t = 0; t < 4; ++t) {
        const bf16x8 vf = *(const bf16x8*)(&Vts[cur][(t * 16 + lm) * 64 + (((kk * 4 + quad) ^ (lm & 7)) * 8)]);
        o_acc[0][t] = __builtin_amdgcn_mfma_f32_16x16x32_bf16(pf[0][kk], vf, o_acc[0][t], 0, 0, 0);
        o_acc[1][t] = __builtin_amdgcn_mfma_f32_16x16x32_bf16(pf[1][kk], vf, o_acc[1][t], 0, 0, 0);
      }
    }
    __builtin_amdgcn_s_setprio(0);

    __syncthreads();                              // drains glds (vmcnt) + orders dbuf swap
  }

#pragma unroll
  for (int g = 0; g < 2; ++g)
#pragma unroll
    for (int r = 0; r < 4; ++r) {
      const float lr = __shfl(l_s[g], quad * 4 + r);
      const float inv = 1.0f / lr;
      const int qg = qt * 128 + wid * 32 + g * 16 + quad * 4 + r;
      if (qg < 1500) {
#pragma unroll
        for (int t = 0; t < 4; ++t)
          Out[((size_t)(b * 1500 + qg)) * 1280 + h * 64 + t * 16 + lm] =
              f2bf(o_acc[g][t][r] * inv);
      }
    }
}

extern "C" void kernel_launch(void* const* d_in, const int* in_sizes, int n_in,
                              void* d_out, int out_size, void* d_ws, size_t ws_size,
                              hipStream_t stream) {
  const float* hs = (const float*)d_in[0];
  const float* Wq = (const float*)d_in[2];
  const float* bq = (const float*)d_in[3];
  const float* Wk = (const float*)d_in[4];
  const float* Wv = (const float*)d_in[5];
  const float* bv = (const float*)d_in[6];
  const float* Wo = (const float*)d_in[7];
  const float* bo = (const float*)d_in[8];

  u16* cvt     = (u16*)d_ws;
  u16* hs_bf   = cvt;                          // [6000,1280]
  u16* Wq_bf   = cvt + 7680000;
  u16* Wk_bf   = cvt + 9318400;
  u16* Wv_bf   = cvt + 10956800;
  u16* Wo_bf   = cvt + 12595200;
  u16* q_ws    = cvt + 14233600;               // [4,20,1500,64]
  u16* k_ws    = q_ws + 7680000;
  u16* vt_ws   = k_ws + 7680000;               // [4,20,64,1504] (+64 pad)
  u16* attn_ws = vt_ws + 7700480 + 64;         // [6000,1280]
  const int M = 6000;

  dim3 blk(256);
  hipLaunchKernelGGL(cvt_kernel, dim3(2048), blk, 0, stream,
                     (const float4*)hs, (const float4*)Wq, (const float4*)Wk,
                     (const float4*)Wv, (const float4*)Wo, cvt);
  hipLaunchKernelGGL(qkv_kernel, dim3(1440), blk, 0, stream,
                     hs_bf, Wq_bf, bq, Wk_bf, Wv_bf, bv, q_ws, k_ws, vt_ws, M);
  hipLaunchKernelGGL(attn_kernel, dim3(12, 20, 4), blk, 0, stream,
                     q_ws, k_ws, vt_ws, attn_ws);
  hipLaunchKernelGGL(out_kernel, dim3(480), blk, 0, stream,
                     attn_ws, Wo_bf, bo, (float*)d_out, M);
}

// Round 4
// 376.399 us; speedup vs baseline: 1.0131x; 1.0131x over previous
//
#include <hip/hip_runtime.h>

typedef unsigned short u16;
using bf16x8 = __attribute__((ext_vector_type(8))) __bf16;
using f32x4  = __attribute__((ext_vector_type(4))) float;
using u32x2  = __attribute__((ext_vector_type(2))) unsigned;
using u32x4  = __attribute__((ext_vector_type(4))) unsigned;

#define AS1 __attribute__((address_space(1)))
#define AS3 __attribute__((address_space(3)))

__device__ __forceinline__ void glds16(const u16* g, u16* l) {
  __builtin_amdgcn_global_load_lds((AS1 void*)const_cast<u16*>(g), (AS3 void*)l, 16, 0, 0);
}

__device__ __forceinline__ u16 f2bf(float f) {
  unsigned u = __float_as_uint(f);
  u += 0x7FFFu + ((u >> 16) & 1u);
  return (u16)(u >> 16);
}
__device__ __forceinline__ ushort4 cvt4(float4 v) {
  return make_ushort4(f2bf(v.x), f2bf(v.y), f2bf(v.z), f2bf(v.w));
}

__device__ __forceinline__ unsigned cvt_pk_bf16(float lo, float hi) {
  unsigned r;
  asm("v_cvt_pk_bf16_f32 %0, %1, %2" : "=v"(r) : "v"(lo), "v"(hi));
  return r;
}

// full quad exchange via permlane32_swap + permlane16_swap (see r0 derivation):
// yields PV A-frag dword pairs from per-lane packed P values.
__device__ __forceinline__ void quad_swap(unsigned& x, unsigned& y) {
  u32x2 a = __builtin_amdgcn_permlane32_swap(x, y, false, false);
  u32x2 b = __builtin_amdgcn_permlane16_swap(a[0], a[1], false, false);
  x = b[0];
  y = b[1];
}

// cross-quad reductions via permlane swaps (VALU, ~4cyc) instead of shfl_xor
// (ds_bpermute, ~120cyc DS round-trip). Lanes lm+16q (q=0..3) hold per-quad
// partials for q-row lm; result is the full reduce, replicated in all 4 lanes.
// permlane16_swap(x,x)->(a,b): a=[r0,r0,r2,r2], b=[r1,r1,r3,r3] (16-lane rows).
// permlane32_swap(y,y)->(a,b): a=[lo,lo], b=[hi,hi] (32-lane halves).
__device__ __forceinline__ float xquad_max(float x) {
  u32x2 a = __builtin_amdgcn_permlane16_swap(__float_as_uint(x), __float_as_uint(x), false, false);
  float y = fmaxf(__uint_as_float(a[0]), __uint_as_float(a[1]));
  u32x2 b = __builtin_amdgcn_permlane32_swap(__float_as_uint(y), __float_as_uint(y), false, false);
  return fmaxf(__uint_as_float(b[0]), __uint_as_float(b[1]));
}
__device__ __forceinline__ float xquad_sum(float x) {
  u32x2 a = __builtin_amdgcn_permlane16_swap(__float_as_uint(x), __float_as_uint(x), false, false);
  float y = __uint_as_float(a[0]) + __uint_as_float(a[1]);
  u32x2 b = __builtin_amdgcn_permlane32_swap(__float_as_uint(y), __float_as_uint(y), false, false);
  return __uint_as_float(b[0]) + __uint_as_float(b[1]);
}

// ---------------- one-shot fp32 -> bf16 conversion ----------------
__global__ __launch_bounds__(256) void cvt_kernel(const float4* __restrict__ hs,
    const float4* __restrict__ wq, const float4* __restrict__ wk,
    const float4* __restrict__ wv, const float4* __restrict__ wo, u16* __restrict__ dst) {
  const long stride = (long)gridDim.x * blockDim.x;
  for (long i = (long)blockIdx.x * blockDim.x + threadIdx.x; i < 3558400; i += stride) {
    const float4* src; long rel; u16* d;
    if (i < 1920000)      { src = hs; rel = i;           d = dst; }
    else if (i < 2329600) { src = wq; rel = i - 1920000; d = dst + 7680000; }
    else if (i < 2739200) { src = wk; rel = i - 2329600; d = dst + 9318400; }
    else if (i < 3148800) { src = wv; rel = i - 2739200; d = dst + 10956800; }
    else                  { src = wo; rel = i - 3148800; d = dst + 12595200; }
    *(ushort4*)(d + rel * 4) = cvt4(src[rel]);
  }
}

// ---------------- bf16 GEMM, 2-phase double-buffered global_load_lds ----------------
// T3-minimum schedule: issue next K-tile's async loads into buf^1, compute buf, one
// barrier/iter (drains vmcnt before s_barrier -> prefetch latency hidden by compute).
// As/Bs are [2][128*32] u16 (16KB each). m0/n0 from callers' XCD-banded remap.
template <int MODE, typename OT>
__device__ __forceinline__ void gemm_bf(const u16* __restrict__ A, const u16* __restrict__ W,
                                        const float* __restrict__ bias, OT* __restrict__ out,
                                        float scale, int M, u16* As, u16* Bs,
                                        int m0, int n0) {
  constexpr int K = 1280;
  constexpr int NIT = K / 32;                   // 40 K-iterations
  const int tid = threadIdx.x, wid = tid >> 6, lane = tid & 63;
  const int lm = lane & 15, quad = lane >> 4;
  const int wm = (wid >> 1) * 64, wn = (wid & 1) * 64;

  f32x4 acc[4][4] = {};

  const int ch0 = wid * 64 + lane, ch1 = 256 + ch0;
  int rA0 = m0 + (ch0 >> 2); rA0 = rA0 < M ? rA0 : M - 1;
  int rA1 = m0 + (ch1 >> 2); rA1 = rA1 < M ? rA1 : M - 1;
  const int kc0 = (ch0 & 3) * 8, kc1 = (ch1 & 3) * 8;
  const u16* a0 = A + (size_t)rA0 * K + kc0;
  const u16* a1 = A + (size_t)rA1 * K + kc1;
  const u16* w0 = W + (size_t)(n0 + (ch0 >> 2)) * K + kc0;
  const u16* w1 = W + (size_t)(n0 + (ch1 >> 2)) * K + kc1;
  u16* lA = As + wid * 512;                     // + bi*4096 selects buffer
  u16* lB = Bs + wid * 512;

  auto stage = [&](int kt, int bi) {
    glds16(a0 + kt, lA + bi * 4096);
    glds16(a1 + kt, lA + bi * 4096 + 2048);
    glds16(w0 + kt, lB + bi * 4096);
    glds16(w1 + kt, lB + bi * 4096 + 2048);
  };

  stage(0, 0);
  __syncthreads();                              // buf0 ready (vmcnt drained pre-barrier)

  for (int it = 0; it < NIT; ++it) {
    const int cur = it & 1;
    if (it + 1 < NIT) stage((it + 1) * 32, cur ^ 1);   // async into other buffer
    const u16* Ab = As + cur * 4096;
    const u16* Bb = Bs + cur * 4096;
    bf16x8 af[4], bfr[4];
#pragma unroll
    for (int i = 0; i < 4; ++i) af[i] = *(const bf16x8*)(Ab + (wm + i * 16 + lm) * 32 + quad * 8);
#pragma unroll
    for (int j = 0; j < 4; ++j) bfr[j] = *(const bf16x8*)(Bb + (wn + j * 16 + lm) * 32 + quad * 8);
#pragma unroll
    for (int i = 0; i < 4; ++i)
#pragma unroll
      for (int j = 0; j < 4; ++j)
        acc[i][j] = __builtin_amdgcn_mfma_f32_16x16x32_bf16(af[i], bfr[j], acc[i][j], 0, 0, 0);
    __syncthreads();                            // next buffer ready; cur safe to overwrite
  }

#pragma unroll
  for (int j = 0; j < 4; ++j) {
    const int col = n0 + wn + j * 16 + lm;
    const float bb = bias ? bias[col] : 0.0f;
    const int hh = col >> 6, dd = col & 63;
#pragma unroll
    for (int i = 0; i < 4; ++i) {
      const int row0 = m0 + wm + i * 16 + quad * 4;
#pragma unroll
      for (int r = 0; r < 4; ++r) {
        const int row = row0 + r;
        if (row < M) {
          const float v = (acc[i][j][r] + bb) * scale;
          if (MODE == 0) {
            out[(size_t)row * 1280 + col] = (OT)v;
          } else {
            const int bidx = row / 1500, s = row - bidx * 1500;
            if (MODE == 1)
              out[((size_t)(bidx * 20 + hh) * 1500 + s) * 64 + dd] = (OT)f2bf(v);
            else
              out[((size_t)(bidx * 20 + hh) * 64 + dd) * 1504 + s] = (OT)f2bf(v);
          }
        }
      }
    }
  }
}

// XCD-banded remap (bijective, m204-style): each XCD owns a contiguous band of
// A-row panels (6,6,6,6,6,6,6,5 over 47) -> per-XCD A working set 1.9MB (L2-fit).
// x innermost so each B panel is consumed while L2-hot.
__global__ __launch_bounds__(256) void qkv_kernel(const u16* __restrict__ hs,
    const u16* __restrict__ Wq, const float* __restrict__ bq, const u16* __restrict__ Wk,
    const u16* __restrict__ Wv, const float* __restrict__ bv,
    u16* __restrict__ q_ws, u16* __restrict__ k_ws, u16* __restrict__ vt_ws, int M) {
  __shared__ __align__(16) u16 As[2 * 128 * 32];
  __shared__ __align__(16) u16 Bs[2 * 128 * 32];
  const int n = blockIdx.x;                     // grid = 1440 (8 XCD * 180)
  const int xcd = n & 7, j = n >> 3;            // j in [0,180)
  const int x = xcd * 6 + (j % 6);
  if (x >= 47) return;                          // block-uniform: safe before barriers
  const int yz = j / 6;                         // [0,30)
  const int y = yz % 10, z = yz / 10;
  const int m0 = x * 128, n0 = y * 128;
  if (z == 0)
    gemm_bf<1, u16>(hs, Wq, bq, q_ws, 0.18033688f, M, As, Bs, m0, n0);  // 0.125*log2(e)
  else if (z == 1)
    gemm_bf<1, u16>(hs, Wk, nullptr, k_ws, 1.0f, M, As, Bs, m0, n0);
  else
    gemm_bf<2, u16>(hs, Wv, bv, vt_ws, 1.0f, M, As, Bs, m0, n0);
}

__global__ __launch_bounds__(256) void out_kernel(const u16* __restrict__ attn,
    const u16* __restrict__ Wo, const float* __restrict__ bo, float* __restrict__ out, int M) {
  __shared__ __align__(16) u16 As[2 * 128 * 32];
  __shared__ __align__(16) u16 Bs[2 * 128 * 32];
  const int n = blockIdx.x;                     // grid = 480 (8 XCD * 60)
  const int xcd = n & 7, j = n >> 3;            // j in [0,60)
  const int x = xcd * 6 + (j % 6);
  if (x >= 47) return;
  const int y = j / 6;                          // [0,10)
  gemm_bf<0, float>(attn, Wo, bo, out, 1.0f, M, As, Bs, x * 128, y * 128);
}

// ---------------- Flash attention: swapped QK^T, in-register softmax/P ----------------
// Q,K: [b,h,1500,64] bf16 (Q pre-scaled by 0.125*log2e); Vt: [b,h,64,1504] bf16.
// 4 waves; wave owns 32 q-rows as 2 groups of 16. S^T = mfma(K,Q): each lane owns one
// q-row (lm) with kpos = t*16+quad*4+r -> per-lane scalar m/l.
// Reductions via permlane swaps (VALU), not DS. T13 defer-max (THR=8 in exp2 domain,
// P<=256): rescale path (alpha bcast + O-mult) only when the running max grows >8.
// P -> bf16 A-frags fully in-register: cvt_pk pairs + permlane32/16_swap quad exchange.
// K/V staged via global_load_lds (pre-swizzled source, linear LDS dest), dbuf, 1 barrier/iter.
__global__ __launch_bounds__(256, 4) void attn_kernel(const u16* __restrict__ Qm,
    const u16* __restrict__ Km, const u16* __restrict__ Vtm, u16* __restrict__ Out) {
  const int qt = blockIdx.x, h = blockIdx.y, b = blockIdx.z;
  const int bh = b * 20 + h;
  const int tid = threadIdx.x, wid = tid >> 6, lane = tid & 63;
  const int lm = lane & 15, quad = lane >> 4;

  __shared__ __align__(16) u16 Ks[2][64 * 64];    // [kpos][d], XOR-chunk swizzled
  __shared__ __align__(16) u16 Vts[2][64 * 64];   // [d][kpos], swizzled

  const u16* Qb = Qm + (size_t)bh * (1500 * 64);
  const u16* Kb = Km + (size_t)bh * (1500 * 64);
  const u16* Vb = Vtm + (size_t)bh * (64 * 1504);

  bf16x8 qf[2][2];
#pragma unroll
  for (int g = 0; g < 2; ++g) {
    int qrow = qt * 128 + wid * 32 + g * 16 + lm;
    if (qrow > 1499) qrow = 1499;                 // dup rows masked at store
    qf[g][0] = *(const bf16x8*)(Qb + (size_t)qrow * 64 + quad * 8);
    qf[g][1] = *(const bf16x8*)(Qb + (size_t)qrow * 64 + 32 + quad * 8);
  }

  // staging geometry: thread (rr, cc) stages 16B chunks; swizzle on the GLOBAL side,
  // LDS dest is linear (wave-uniform base + lane*16B) as global_load_lds requires.
  const int rr = tid >> 3, cc = tid & 7;
  const int s0 = (cc ^ (rr & 7)) * 8;             // (rr+32)&7 == rr&7

  auto stage = [&](int kt, int bi) {
    int kr0 = kt + rr;      if (kr0 > 1499) kr0 = 1499;
    int kr1 = kt + rr + 32; if (kr1 > 1499) kr1 = 1499;
    int vcol = kt + s0;     if (vcol > 1496) vcol = 1496;   // keep V reads in-bounds/finite
    u16* lk = &Ks[bi][0] + wid * 512;
    u16* lv = &Vts[bi][0] + wid * 512;
    glds16(Kb + (size_t)kr0 * 64 + s0, lk);
    glds16(Kb + (size_t)kr1 * 64 + s0, lk + 2048);
    glds16(Vb + (size_t)rr * 1504 + vcol, lv);
    glds16(Vb + (size_t)(rr + 32) * 1504 + vcol, lv + 2048);
  };

  stage(0, 0);
  __syncthreads();

  float m_s[2] = {-1e30f, -1e30f};
  float l_s[2] = {0.f, 0.f};
  f32x4 o_acc[2][4] = {};

  for (int it = 0; it < 24; ++it) {
    const int cur = it & 1;
    if (it + 1 < 24) stage((it + 1) * 64, cur ^ 1);   // async into other buffer

    // S^T = K Q^T : st[g][t] lane holds q-row lm, kpos = t*16 + quad*4 + r
    f32x4 st[2][4] = {};
    __builtin_amdgcn_s_setprio(1);
#pragma unroll
    for (int kk = 0; kk < 2; ++kk) {
#pragma unroll
      for (int t = 0; t < 4; ++t) {
        const bf16x8 kf = *(const bf16x8*)(&Ks[cur][(t * 16 + lm) * 64 + (((kk * 4 + quad) ^ (lm & 7)) * 8)]);
        st[0][t] = __builtin_amdgcn_mfma_f32_16x16x32_bf16(kf, qf[0][kk], st[0][t], 0, 0, 0);
        st[1][t] = __builtin_amdgcn_mfma_f32_16x16x32_bf16(kf, qf[1][kk], st[1][t], 0, 0, 0);
      }
    }
    __builtin_amdgcn_s_setprio(0);
    if (it == 23) {                               // ragged tile: kpos = 1472 + t*16+quad*4+r
#pragma unroll
      for (int t = 0; t < 4; ++t)
#pragma unroll
        for (int r = 0; r < 4; ++r)
          if (t * 16 + quad * 4 + r >= 28) { st[0][t][r] = -1e30f; st[1][t][r] = -1e30f; }
    }

    bf16x8 pf[2][2];
#pragma unroll
    for (int g = 0; g < 2; ++g) {
      // tile row max: in-lane tree over 16 + 2 permlane swaps (all on VALU)
      float a0 = fmaxf(fmaxf(st[g][0][0], st[g][0][1]), fmaxf(st[g][0][2], st[g][0][3]));
      float a1 = fmaxf(fmaxf(st[g][1][0], st[g][1][1]), fmaxf(st[g][1][2], st[g][1][3]));
      float a2 = fmaxf(fmaxf(st[g][2][0], st[g][2][1]), fmaxf(st[g][2][2], st[g][2][3]));
      float a3 = fmaxf(fmaxf(st[g][3][0], st[g][3][1]), fmaxf(st[g][3][2], st[g][3][3]));
      float rm = xquad_max(fmaxf(fmaxf(a0, a1), fmaxf(a2, a3)));

      // T13 defer-max: rescale only when the running max grows by >8 (exp2 domain,
      // so skipped-path P <= 2^8 = 256; bf16/f32 accumulation tolerates). Wave-uniform.
      if (!__all(rm - m_s[g] <= 8.0f)) {
        const float mn = fmaxf(m_s[g], rm);
        const float al = exp2f(m_s[g] - mn);      // first iter: exp2(-inf) = 0
        m_s[g] = mn;
        l_s[g] *= al;
        // broadcast alpha into accumulator layout (q-row = quad*4+r) and rescale O
#pragma unroll
        for (int r = 0; r < 4; ++r) {
          const float ao = __shfl(al, quad * 4 + r);
#pragma unroll
          for (int t = 0; t < 4; ++t) o_acc[g][t][r] *= ao;
        }
      }
      const float mn = m_s[g];

      float rs = 0.f;
      unsigned A[4], B[4];
#pragma unroll
      for (int t = 0; t < 4; ++t) {
        const float p0 = exp2f(st[g][t][0] - mn);
        const float p1 = exp2f(st[g][t][1] - mn);
        const float p2 = exp2f(st[g][t][2] - mn);
        const float p3 = exp2f(st[g][t][3] - mn);
        rs += (p0 + p1) + (p2 + p3);
        A[t] = cvt_pk_bf16(p0, p1);
        B[t] = cvt_pk_bf16(p2, p3);
      }
      l_s[g] += xquad_sum(rs);                    // off the PV critical path

      // redistribute P into PV A-frag layout: lane ends with P[lm][kk*32+quad*8 .. +7]
#pragma unroll
      for (int kk = 0; kk < 2; ++kk) {
        unsigned x0 = A[2 * kk], x1 = A[2 * kk + 1];
        quad_swap(x0, x1);                        // -> dwords 0 (k+0,1) and 2 (k+4,5)
        unsigned y0 = B[2 * kk], y1 = B[2 * kk + 1];
        quad_swap(y0, y1);                        // -> dwords 1 (k+2,3) and 3 (k+6,7)
        u32x4 w; w[0] = x0; w[1] = y0; w[2] = x1; w[3] = y1;
        pf[g][kk] = __builtin_bit_cast(bf16x8, w);
      }
    }

    // O += P V
    __builtin_amdgcn_s_setprio(1);
#pragma unroll
    for (int kk = 0; kk < 2; ++kk) {
#pragma unroll
      for (int t = 0; t < 4; ++t) {
        const bf16x8 vf = *(const bf16x8*)(&Vts[cur][(t * 16 + lm) * 64 + (((kk * 4 + quad) ^ (lm & 7)) * 8)]);
        o_acc[0][t] = __builtin_amdgcn_mfma_f32_16x16x32_bf16(pf[0][kk], vf, o_acc[0][t], 0, 0, 0);
        o_acc[1][t] = __builtin_amdgcn_mfma_f32_16x16x32_bf16(pf[1][kk], vf, o_acc[1][t], 0, 0, 0);
      }
    }
    __builtin_amdgcn_s_setprio(0);

    __syncthreads();                              // drains glds (vmcnt) + orders dbuf swap
  }

#pragma unroll
  for (int g = 0; g < 2; ++g)
#pragma unroll
    for (int r = 0; r < 4; ++r) {
      const float lr = __shfl(l_s[g], quad * 4 + r);
      const float inv = 1.0f / lr;
      const int qg = qt * 128 + wid * 32 + g * 16 + quad * 4 + r;
      if (qg < 1500) {
#pragma unroll
        for (int t = 0; t < 4; ++t)
          Out[((size_t)(b * 1500 + qg)) * 1280 + h * 64 + t * 16 + lm] =
              f2bf(o_acc[g][t][r] * inv);
      }
    }
}

extern "C" void kernel_launch(void* const* d_in, const int* in_sizes, int n_in,
                              void* d_out, int out_size, void* d_ws, size_t ws_size,
                              hipStream_t stream) {
  const float* hs = (const float*)d_in[0];
  const float* Wq = (const float*)d_in[2];
  const float* bq = (const float*)d_in[3];
  const float* Wk = (const float*)d_in[4];
  const float* Wv = (const float*)d_in[5];
  const float* bv = (const float*)d_in[6];
  const float* Wo = (const float*)d_in[7];
  const float* bo = (const float*)d_in[8];

  u16* cvt     = (u16*)d_ws;
  u16* hs_bf   = cvt;                          // [6000,1280]
  u16* Wq_bf   = cvt + 7680000;
  u16* Wk_bf   = cvt + 9318400;
  u16* Wv_bf   = cvt + 10956800;
  u16* Wo_bf   = cvt + 12595200;
  u16* q_ws    = cvt + 14233600;               // [4,20,1500,64]
  u16* k_ws    = q_ws + 7680000;
  u16* vt_ws   = k_ws + 7680000;               // [4,20,64,1504] (+64 pad)
  u16* attn_ws = vt_ws + 7700480 + 64;         // [6000,1280]
  const int M = 6000;

  dim3 blk(256);
  hipLaunchKernelGGL(cvt_kernel, dim3(2048), blk, 0, stream,
                     (const float4*)hs, (const float4*)Wq, (const float4*)Wk,
                     (const float4*)Wv, (const float4*)Wo, cvt);
  hipLaunchKernelGGL(qkv_kernel, dim3(1440), blk, 0, stream,
                     hs_bf, Wq_bf, bq, Wk_bf, Wv_bf, bv, q_ws, k_ws, vt_ws, M);
  hipLaunchKernelGGL(attn_kernel, dim3(12, 20, 4), blk, 0, stream,
                     q_ws, k_ws, vt_ws, attn_ws);
  hipLaunchKernelGGL(out_kernel, dim3(480), blk, 0, stream,
                     attn_ws, Wo_bf, bo, (float*)d_out, M);
}

// Round 5
// 371.593 us; speedup vs baseline: 1.0262x; 1.0129x over previous
//
#include <hip/hip_runtime.h>

typedef unsigned short u16;
using bf16x8 = __attribute__((ext_vector_type(8))) __bf16;
using f32x4  = __attribute__((ext_vector_type(4))) float;
using u32x2  = __attribute__((ext_vector_type(2))) unsigned;
using u32x4  = __attribute__((ext_vector_type(4))) unsigned;

#define AS1 __attribute__((address_space(1)))
#define AS3 __attribute__((address_space(3)))

__device__ __forceinline__ void glds16(const u16* g, u16* l) {
  __builtin_amdgcn_global_load_lds((AS1 void*)const_cast<u16*>(g), (AS3 void*)l, 16, 0, 0);
}

__device__ __forceinline__ u16 f2bf(float f) {
  unsigned u = __float_as_uint(f);
  u += 0x7FFFu + ((u >> 16) & 1u);
  return (u16)(u >> 16);
}
__device__ __forceinline__ ushort4 cvt4(float4 v) {
  return make_ushort4(f2bf(v.x), f2bf(v.y), f2bf(v.z), f2bf(v.w));
}

__device__ __forceinline__ unsigned cvt_pk_bf16(float lo, float hi) {
  unsigned r;
  asm("v_cvt_pk_bf16_f32 %0, %1, %2" : "=v"(r) : "v"(lo), "v"(hi));
  return r;
}

// full quad exchange via permlane32_swap + permlane16_swap (see r0 derivation):
// yields PV A-frag dword pairs from per-lane packed P values.
__device__ __forceinline__ void quad_swap(unsigned& x, unsigned& y) {
  u32x2 a = __builtin_amdgcn_permlane32_swap(x, y, false, false);
  u32x2 b = __builtin_amdgcn_permlane16_swap(a[0], a[1], false, false);
  x = b[0];
  y = b[1];
}

// cross-quad reductions via permlane swaps (VALU, ~4cyc) instead of shfl_xor
// (ds_bpermute, ~120cyc DS round-trip). Result replicated in all 4 quads.
__device__ __forceinline__ float xquad_max(float x) {
  u32x2 a = __builtin_amdgcn_permlane16_swap(__float_as_uint(x), __float_as_uint(x), false, false);
  float y = fmaxf(__uint_as_float(a[0]), __uint_as_float(a[1]));
  u32x2 b = __builtin_amdgcn_permlane32_swap(__float_as_uint(y), __float_as_uint(y), false, false);
  return fmaxf(__uint_as_float(b[0]), __uint_as_float(b[1]));
}
__device__ __forceinline__ float xquad_sum(float x) {
  u32x2 a = __builtin_amdgcn_permlane16_swap(__float_as_uint(x), __float_as_uint(x), false, false);
  float y = __uint_as_float(a[0]) + __uint_as_float(a[1]);
  u32x2 b = __builtin_amdgcn_permlane32_swap(__float_as_uint(y), __float_as_uint(y), false, false);
  return __uint_as_float(b[0]) + __uint_as_float(b[1]);
}

// ---------------- one-shot fp32 -> bf16 conversion ----------------
__global__ __launch_bounds__(256) void cvt_kernel(const float4* __restrict__ hs,
    const float4* __restrict__ wq, const float4* __restrict__ wk,
    const float4* __restrict__ wv, const float4* __restrict__ wo, u16* __restrict__ dst) {
  const long stride = (long)gridDim.x * blockDim.x;
  for (long i = (long)blockIdx.x * blockDim.x + threadIdx.x; i < 3558400; i += stride) {
    const float4* src; long rel; u16* d;
    if (i < 1920000)      { src = hs; rel = i;           d = dst; }
    else if (i < 2329600) { src = wq; rel = i - 1920000; d = dst + 7680000; }
    else if (i < 2739200) { src = wk; rel = i - 2329600; d = dst + 9318400; }
    else if (i < 3148800) { src = wv; rel = i - 2739200; d = dst + 10956800; }
    else                  { src = wo; rel = i - 3148800; d = dst + 12595200; }
    *(ushort4*)(d + rel * 4) = cvt4(src[rel]);
  }
}

// ---------------- bf16 GEMM, BK=64, swizzled LDS, 2-phase dbuf ----------------
// Tiles [128 rows][64 k] per matrix per buffer (16KB), rows = 128B = 8 slots of 16B.
// XOR swizzle (attn-proven, 0 conflicts): LDS[row][slot] holds global k-chunk
// (slot ^ (row&7)); staged via pre-swizzled GLOBAL col + linear LDS dest
// (global_load_lds requirement). Frag read slot = (kk*4+quad) ^ (lm&7).
// 20 K-iterations (vs 40 at BK=32) -> half the barrier/vmcnt(0) drains.
template <int MODE, typename OT>
__device__ __forceinline__ void gemm_bf(const u16* __restrict__ A, const u16* __restrict__ W,
                                        const float* __restrict__ bias, OT* __restrict__ out,
                                        float scale, int M, u16* As, u16* Bs,
                                        int m0, int n0) {
  constexpr int K = 1280;
  constexpr int NIT = K / 64;                   // 20 K-iterations
  const int tid = threadIdx.x, wid = tid >> 6, lane = tid & 63;
  const int lm = lane & 15, quad = lane >> 4;
  const int wm = (wid >> 1) * 64, wn = (wid & 1) * 64;

  f32x4 acc[4][4] = {};

  // staging: 16KB per matrix per K-tile = 4 glds insts of 256 lanes x 16B.
  // chunk c = i*256 + tid: row = i*32 + (tid>>3), slot = tid&7,
  // global col = (slot ^ (row&7))*8  (pre-swizzled source, linear LDS dest).
  const int srow = tid >> 3, sslot = tid & 7;
  const u16* ag[4]; const u16* wg[4];
#pragma unroll
  for (int i = 0; i < 4; ++i) {
    const int row = i * 32 + srow;
    const int gc = (sslot ^ (row & 7)) * 8;
    int ra = m0 + row; ra = ra < M ? ra : M - 1;        // dup rows masked at store
    ag[i] = A + (size_t)ra * K + gc;
    wg[i] = W + (size_t)(n0 + row) * K + gc;
  }
  u16* lA = As + wid * 512;                     // inst i dest: + i*2048 (+ bi*8192)
  u16* lB = Bs + wid * 512;

  auto stage = [&](int kt, int bi) {
#pragma unroll
    for (int i = 0; i < 4; ++i) {
      glds16(ag[i] + kt, lA + bi * 8192 + i * 2048);
      glds16(wg[i] + kt, lB + bi * 8192 + i * 2048);
    }
  };

  stage(0, 0);
  __syncthreads();                              // buf0 ready (vmcnt drained pre-barrier)

  // frag read slot offsets (u16): row&7 == lm&7 since wm, i*16 are mult of 8
  const int coff0 = ((0 + quad) ^ (lm & 7)) * 8;
  const int coff1 = ((4 + quad) ^ (lm & 7)) * 8;

  for (int it = 0; it < NIT; ++it) {
    const int cur = it & 1;
    if (it + 1 < NIT) stage((it + 1) * 64, cur ^ 1);   // async into other buffer
    const u16* Ab = As + cur * 8192;
    const u16* Bb = Bs + cur * 8192;
#pragma unroll
    for (int kk = 0; kk < 2; ++kk) {
      const int co = kk ? coff1 : coff0;
      bf16x8 af[4], bfr[4];
#pragma unroll
      for (int i = 0; i < 4; ++i) af[i] = *(const bf16x8*)(Ab + (wm + i * 16 + lm) * 64 + co);
#pragma unroll
      for (int j = 0; j < 4; ++j) bfr[j] = *(const bf16x8*)(Bb + (wn + j * 16 + lm) * 64 + co);
#pragma unroll
      for (int i = 0; i < 4; ++i)
#pragma unroll
        for (int j = 0; j < 4; ++j)
          acc[i][j] = __builtin_amdgcn_mfma_f32_16x16x32_bf16(af[i], bfr[j], acc[i][j], 0, 0, 0);
    }
    __syncthreads();                            // next buffer ready; cur safe to overwrite
  }

#pragma unroll
  for (int j = 0; j < 4; ++j) {
    const int col = n0 + wn + j * 16 + lm;
    const float bb = bias ? bias[col] : 0.0f;
    const int hh = col >> 6, dd = col & 63;
#pragma unroll
    for (int i = 0; i < 4; ++i) {
      const int row0 = m0 + wm + i * 16 + quad * 4;
#pragma unroll
      for (int r = 0; r < 4; ++r) {
        const int row = row0 + r;
        if (row < M) {
          const float v = (acc[i][j][r] + bb) * scale;
          if (MODE == 0) {
            out[(size_t)row * 1280 + col] = (OT)v;
          } else {
            const int bidx = row / 1500, s = row - bidx * 1500;
            if (MODE == 1)
              out[((size_t)(bidx * 20 + hh) * 1500 + s) * 64 + dd] = (OT)f2bf(v);
            else
              out[((size_t)(bidx * 20 + hh) * 64 + dd) * 1504 + s] = (OT)f2bf(v);
          }
        }
      }
    }
  }
}

// XCD-banded remap (bijective, m204-style): each XCD owns a contiguous band of
// A-row panels (6,6,6,6,6,6,6,5 over 47) -> per-XCD A working set 1.9MB (L2-fit).
// x innermost so each B panel is consumed while L2-hot.
__global__ __launch_bounds__(256) void qkv_kernel(const u16* __restrict__ hs,
    const u16* __restrict__ Wq, const float* __restrict__ bq, const u16* __restrict__ Wk,
    const u16* __restrict__ Wv, const float* __restrict__ bv,
    u16* __restrict__ q_ws, u16* __restrict__ k_ws, u16* __restrict__ vt_ws, int M) {
  __shared__ __align__(16) u16 As[2 * 128 * 64];
  __shared__ __align__(16) u16 Bs[2 * 128 * 64];
  const int n = blockIdx.x;                     // grid = 1440 (8 XCD * 180)
  const int xcd = n & 7, j = n >> 3;            // j in [0,180)
  const int x = xcd * 6 + (j % 6);
  if (x >= 47) return;                          // block-uniform: safe before barriers
  const int yz = j / 6;                         // [0,30)
  const int y = yz % 10, z = yz / 10;
  const int m0 = x * 128, n0 = y * 128;
  if (z == 0)
    gemm_bf<1, u16>(hs, Wq, bq, q_ws, 0.18033688f, M, As, Bs, m0, n0);  // 0.125*log2(e)
  else if (z == 1)
    gemm_bf<1, u16>(hs, Wk, nullptr, k_ws, 1.0f, M, As, Bs, m0, n0);
  else
    gemm_bf<2, u16>(hs, Wv, bv, vt_ws, 1.0f, M, As, Bs, m0, n0);
}

__global__ __launch_bounds__(256) void out_kernel(const u16* __restrict__ attn,
    const u16* __restrict__ Wo, const float* __restrict__ bo, float* __restrict__ out, int M) {
  __shared__ __align__(16) u16 As[2 * 128 * 64];
  __shared__ __align__(16) u16 Bs[2 * 128 * 64];
  const int n = blockIdx.x;                     // grid = 480 (8 XCD * 60)
  const int xcd = n & 7, j = n >> 3;            // j in [0,60)
  const int x = xcd * 6 + (j % 6);
  if (x >= 47) return;
  const int y = j / 6;                          // [0,10)
  gemm_bf<0, float>(attn, Wo, bo, out, 1.0f, M, As, Bs, x * 128, y * 128);
}

// ---------------- Flash attention: swapped QK^T, in-register softmax/P ----------------
// Q,K: [b,h,1500,64] bf16 (Q pre-scaled by 0.125*log2e); Vt: [b,h,64,1504] bf16.
// 4 waves; wave owns 32 q-rows as 2 groups of 16. S^T = mfma(K,Q): each lane owns one
// q-row (lm) with kpos = t*16+quad*4+r -> per-lane scalar m/l.
// Reductions via permlane swaps (VALU), not DS. T13 defer-max (THR=8 in exp2 domain,
// P<=256): rescale path (alpha bcast + O-mult) only when the running max grows >8.
// P -> bf16 A-frags fully in-register: cvt_pk pairs + permlane32/16_swap quad exchange.
// K/V staged via global_load_lds (pre-swizzled source, linear LDS dest), dbuf, 1 barrier/iter.
__global__ __launch_bounds__(256, 4) void attn_kernel(const u16* __restrict__ Qm,
    const u16* __restrict__ Km, const u16* __restrict__ Vtm, u16* __restrict__ Out) {
  const int qt = blockIdx.x, h = blockIdx.y, b = blockIdx.z;
  const int bh = b * 20 + h;
  const int tid = threadIdx.x, wid = tid >> 6, lane = tid & 63;
  const int lm = lane & 15, quad = lane >> 4;

  __shared__ __align__(16) u16 Ks[2][64 * 64];    // [kpos][d], XOR-chunk swizzled
  __shared__ __align__(16) u16 Vts[2][64 * 64];   // [d][kpos], swizzled

  const u16* Qb = Qm + (size_t)bh * (1500 * 64);
  const u16* Kb = Km + (size_t)bh * (1500 * 64);
  const u16* Vb = Vtm + (size_t)bh * (64 * 1504);

  bf16x8 qf[2][2];
#pragma unroll
  for (int g = 0; g < 2; ++g) {
    int qrow = qt * 128 + wid * 32 + g * 16 + lm;
    if (qrow > 1499) qrow = 1499;                 // dup rows masked at store
    qf[g][0] = *(const bf16x8*)(Qb + (size_t)qrow * 64 + quad * 8);
    qf[g][1] = *(const bf16x8*)(Qb + (size_t)qrow * 64 + 32 + quad * 8);
  }

  // staging geometry: thread (rr, cc) stages 16B chunks; swizzle on the GLOBAL side,
  // LDS dest is linear (wave-uniform base + lane*16B) as global_load_lds requires.
  const int rr = tid >> 3, cc = tid & 7;
  const int s0 = (cc ^ (rr & 7)) * 8;             // (rr+32)&7 == rr&7

  auto stage = [&](int kt, int bi) {
    int kr0 = kt + rr;      if (kr0 > 1499) kr0 = 1499;
    int kr1 = kt + rr + 32; if (kr1 > 1499) kr1 = 1499;
    int vcol = kt + s0;     if (vcol > 1496) vcol = 1496;   // keep V reads in-bounds/finite
    u16* lk = &Ks[bi][0] + wid * 512;
    u16* lv = &Vts[bi][0] + wid * 512;
    glds16(Kb + (size_t)kr0 * 64 + s0, lk);
    glds16(Kb + (size_t)kr1 * 64 + s0, lk + 2048);
    glds16(Vb + (size_t)rr * 1504 + vcol, lv);
    glds16(Vb + (size_t)(rr + 32) * 1504 + vcol, lv + 2048);
  };

  stage(0, 0);
  __syncthreads();

  float m_s[2] = {-1e30f, -1e30f};
  float l_s[2] = {0.f, 0.f};
  f32x4 o_acc[2][4] = {};

  for (int it = 0; it < 24; ++it) {
    const int cur = it & 1;
    if (it + 1 < 24) stage((it + 1) * 64, cur ^ 1);   // async into other buffer

    // S^T = K Q^T : st[g][t] lane holds q-row lm, kpos = t*16 + quad*4 + r
    f32x4 st[2][4] = {};
    __builtin_amdgcn_s_setprio(1);
#pragma unroll
    for (int kk = 0; kk < 2; ++kk) {
#pragma unroll
      for (int t = 0; t < 4; ++t) {
        const bf16x8 kf = *(const bf16x8*)(&Ks[cur][(t * 16 + lm) * 64 + (((kk * 4 + quad) ^ (lm & 7)) * 8)]);
        st[0][t] = __builtin_amdgcn_mfma_f32_16x16x32_bf16(kf, qf[0][kk], st[0][t], 0, 0, 0);
        st[1][t] = __builtin_amdgcn_mfma_f32_16x16x32_bf16(kf, qf[1][kk], st[1][t], 0, 0, 0);
      }
    }
    __builtin_amdgcn_s_setprio(0);
    if (it == 23) {                               // ragged tile: kpos = 1472 + t*16+quad*4+r
#pragma unroll
      for (int t = 0; t < 4; ++t)
#pragma unroll
        for (int r = 0; r < 4; ++r)
          if (t * 16 + quad * 4 + r >= 28) { st[0][t][r] = -1e30f; st[1][t][r] = -1e30f; }
    }

    bf16x8 pf[2][2];
#pragma unroll
    for (int g = 0; g < 2; ++g) {
      // tile row max: in-lane tree over 16 + 2 permlane swaps (all on VALU)
      float a0 = fmaxf(fmaxf(st[g][0][0], st[g][0][1]), fmaxf(st[g][0][2], st[g][0][3]));
      float a1 = fmaxf(fmaxf(st[g][1][0], st[g][1][1]), fmaxf(st[g][1][2], st[g][1][3]));
      float a2 = fmaxf(fmaxf(st[g][2][0], st[g][2][1]), fmaxf(st[g][2][2], st[g][2][3]));
      float a3 = fmaxf(fmaxf(st[g][3][0], st[g][3][1]), fmaxf(st[g][3][2], st[g][3][3]));
      float rm = xquad_max(fmaxf(fmaxf(a0, a1), fmaxf(a2, a3)));

      // T13 defer-max: rescale only when the running max grows by >8 (exp2 domain,
      // so skipped-path P <= 2^8 = 256; bf16/f32 accumulation tolerates). Wave-uniform.
      if (!__all(rm - m_s[g] <= 8.0f)) {
        const float mn = fmaxf(m_s[g], rm);
        const float al = exp2f(m_s[g] - mn);      // first iter: exp2(-inf) = 0
        m_s[g] = mn;
        l_s[g] *= al;
        // broadcast alpha into accumulator layout (q-row = quad*4+r) and rescale O
#pragma unroll
        for (int r = 0; r < 4; ++r) {
          const float ao = __shfl(al, quad * 4 + r);
#pragma unroll
          for (int t = 0; t < 4; ++t) o_acc[g][t][r] *= ao;
        }
      }
      const float mn = m_s[g];

      float rs = 0.f;
      unsigned A[4], B[4];
#pragma unroll
      for (int t = 0; t < 4; ++t) {
        const float p0 = exp2f(st[g][t][0] - mn);
        const float p1 = exp2f(st[g][t][1] - mn);
        const float p2 = exp2f(st[g][t][2] - mn);
        const float p3 = exp2f(st[g][t][3] - mn);
        rs += (p0 + p1) + (p2 + p3);
        A[t] = cvt_pk_bf16(p0, p1);
        B[t] = cvt_pk_bf16(p2, p3);
      }
      l_s[g] += xquad_sum(rs);                    // off the PV critical path

      // redistribute P into PV A-frag layout: lane ends with P[lm][kk*32+quad*8 .. +7]
#pragma unroll
      for (int kk = 0; kk < 2; ++kk) {
        unsigned x0 = A[2 * kk], x1 = A[2 * kk + 1];
        quad_swap(x0, x1);                        // -> dwords 0 (k+0,1) and 2 (k+4,5)
        unsigned y0 = B[2 * kk], y1 = B[2 * kk + 1];
        quad_swap(y0, y1);                        // -> dwords 1 (k+2,3) and 3 (k+6,7)
        u32x4 w; w[0] = x0; w[1] = y0; w[2] = x1; w[3] = y1;
        pf[g][kk] = __builtin_bit_cast(bf16x8, w);
      }
    }

    // O += P V
    __builtin_amdgcn_s_setprio(1);
#pragma unroll
    for (int kk = 0; kk < 2; ++kk) {
#pragma unroll
      for (int t = 0; t < 4; ++t) {
        const bf16x8 vf = *(const bf16x8*)(&Vts[cur][(t * 16 + lm) * 64 + (((kk * 4 + quad) ^ (lm & 7)) * 8)]);
        o_acc[0][t] = __builtin_amdgcn_mfma_f32_16x16x32_bf16(pf[0][kk], vf, o_acc[0][t], 0, 0, 0);
        o_acc[1][t] = __builtin_amdgcn_mfma_f32_16x16x32_bf16(pf[1][kk], vf, o_acc[1][t], 0, 0, 0);
      }
    }
    __builtin_amdgcn_s_setprio(0);

    __syncthreads();                              // drains glds (vmcnt) + orders dbuf swap
  }

#pragma unroll
  for (int g = 0; g < 2; ++g)
#pragma unroll
    for (int r = 0; r < 4; ++r) {
      const float lr = __shfl(l_s[g], quad * 4 + r);
      const float inv = 1.0f / lr;
      const int qg = qt * 128 + wid * 32 + g * 16 + quad * 4 + r;
      if (qg < 1500) {
#pragma unroll
        for (int t = 0; t < 4; ++t)
          Out[((size_t)(b * 1500 + qg)) * 1280 + h * 64 + t * 16 + lm] =
              f2bf(o_acc[g][t][r] * inv);
      }
    }
}

extern "C" void kernel_launch(void* const* d_in, const int* in_sizes, int n_in,
                              void* d_out, int out_size, void* d_ws, size_t ws_size,
                              hipStream_t stream) {
  const float* hs = (const float*)d_in[0];
  const float* Wq = (const float*)d_in[2];
  const float* bq = (const float*)d_in[3];
  const float* Wk = (const float*)d_in[4];
  const float* Wv = (const float*)d_in[5];
  const float* bv = (const float*)d_in[6];
  const float* Wo = (const float*)d_in[7];
  const float* bo = (const float*)d_in[8];

  u16* cvt     = (u16*)d_ws;
  u16* hs_bf   = cvt;                          // [6000,1280]
  u16* Wq_bf   = cvt + 7680000;
  u16* Wk_bf   = cvt + 9318400;
  u16* Wv_bf   = cvt + 10956800;
  u16* Wo_bf   = cvt + 12595200;
  u16* q_ws    = cvt + 14233600;               // [4,20,1500,64]
  u16* k_ws    = q_ws + 7680000;
  u16* vt_ws   = k_ws + 7680000;               // [4,20,64,1504] (+64 pad)
  u16* attn_ws = vt_ws + 7700480 + 64;         // [6000,1280]
  const int M = 6000;

  dim3 blk(256);
  hipLaunchKernelGGL(cvt_kernel, dim3(2048), blk, 0, stream,
                     (const float4*)hs, (const float4*)Wq, (const float4*)Wk,
                     (const float4*)Wv, (const float4*)Wo, cvt);
  hipLaunchKernelGGL(qkv_kernel, dim3(1440), blk, 0, stream,
                     hs_bf, Wq_bf, bq, Wk_bf, Wv_bf, bv, q_ws, k_ws, vt_ws, M);
  hipLaunchKernelGGL(attn_kernel, dim3(12, 20, 4), blk, 0, stream,
                     q_ws, k_ws, vt_ws, attn_ws);
  hipLaunchKernelGGL(out_kernel, dim3(480), blk, 0, stream,
                     attn_ws, Wo_bf, bo, (float*)d_out, M);
}

// Round 6
// 355.093 us; speedup vs baseline: 1.0739x; 1.0465x over previous
//
#include <hip/hip_runtime.h>

typedef unsigned short u16;
using bf16x8 = __attribute__((ext_vector_type(8))) __bf16;
using f32x4  = __attribute__((ext_vector_type(4))) float;
using u32x2  = __attribute__((ext_vector_type(2))) unsigned;
using u32x4  = __attribute__((ext_vector_type(4))) unsigned;

#define AS1 __attribute__((address_space(1)))
#define AS3 __attribute__((address_space(3)))

__device__ __forceinline__ void glds16(const u16* g, u16* l) {
  __builtin_amdgcn_global_load_lds((AS1 void*)const_cast<u16*>(g), (AS3 void*)l, 16, 0, 0);
}

__device__ __forceinline__ u16 f2bf(float f) {
  unsigned u = __float_as_uint(f);
  u += 0x7FFFu + ((u >> 16) & 1u);
  return (u16)(u >> 16);
}
__device__ __forceinline__ ushort4 cvt4(float4 v) {
  return make_ushort4(f2bf(v.x), f2bf(v.y), f2bf(v.z), f2bf(v.w));
}

__device__ __forceinline__ unsigned cvt_pk_bf16(float lo, float hi) {
  unsigned r;
  asm("v_cvt_pk_bf16_f32 %0, %1, %2" : "=v"(r) : "v"(lo), "v"(hi));
  return r;
}

// full quad exchange via permlane32_swap + permlane16_swap (r0 derivation):
// yields PV A-frag dword pairs from per-lane packed P values.
__device__ __forceinline__ void quad_swap(unsigned& x, unsigned& y) {
  u32x2 a = __builtin_amdgcn_permlane32_swap(x, y, false, false);
  u32x2 b = __builtin_amdgcn_permlane16_swap(a[0], a[1], false, false);
  x = b[0];
  y = b[1];
}

// cross-quad reductions via permlane swaps (VALU) instead of DS round-trips.
__device__ __forceinline__ float xquad_max(float x) {
  u32x2 a = __builtin_amdgcn_permlane16_swap(__float_as_uint(x), __float_as_uint(x), false, false);
  float y = fmaxf(__uint_as_float(a[0]), __uint_as_float(a[1]));
  u32x2 b = __builtin_amdgcn_permlane32_swap(__float_as_uint(y), __float_as_uint(y), false, false);
  return fmaxf(__uint_as_float(b[0]), __uint_as_float(b[1]));
}
__device__ __forceinline__ float xquad_sum(float x) {
  u32x2 a = __builtin_amdgcn_permlane16_swap(__float_as_uint(x), __float_as_uint(x), false, false);
  float y = __uint_as_float(a[0]) + __uint_as_float(a[1]);
  u32x2 b = __builtin_amdgcn_permlane32_swap(__float_as_uint(y), __float_as_uint(y), false, false);
  return __uint_as_float(b[0]) + __uint_as_float(b[1]);
}

// ---------------- one-shot fp32 -> bf16 conversion ----------------
__global__ __launch_bounds__(256) void cvt_kernel(const float4* __restrict__ hs,
    const float4* __restrict__ wq, const float4* __restrict__ wk,
    const float4* __restrict__ wv, const float4* __restrict__ wo, u16* __restrict__ dst) {
  const long stride = (long)gridDim.x * blockDim.x;
  for (long i = (long)blockIdx.x * blockDim.x + threadIdx.x; i < 3558400; i += stride) {
    const float4* src; long rel; u16* d;
    if (i < 1920000)      { src = hs; rel = i;           d = dst; }
    else if (i < 2329600) { src = wq; rel = i - 1920000; d = dst + 7680000; }
    else if (i < 2739200) { src = wk; rel = i - 2329600; d = dst + 9318400; }
    else if (i < 3148800) { src = wv; rel = i - 2739200; d = dst + 10956800; }
    else                  { src = wo; rel = i - 3148800; d = dst + 12595200; }
    *(ushort4*)(d + rel * 4) = cvt4(src[rel]);
  }
}

// ---------------- bf16 GEMM: 256x128 tile, BK=64, 3-stage counted-vmcnt pipeline ----
// T3+T4: 3 LDS buffers (48KB each: A 256x64 + B 128x64). While computing tile t
// (buf t%3), the 6 glds for tile t+2 are issued into buf (t+2)%3 (last read by tile
// t-1, finished before the boundary barrier those glds follow -> no WAR hazard).
// Tile boundary: s_waitcnt vmcnt(6) (tile t+1's 6 loads are the ONLY ones allowed to
// remain in flight) + raw s_barrier. No vmcnt(0) in the main loop (T4, m218).
// Per K-tile: 2 phases {8 swizzled ds_read_b128 || 3 glds, s_barrier, setprio(1),
// 16 MFMA, setprio(0), s_barrier}  (m196/m201 phase shape).
// 8 waves = 4M x 2N, wave output 64x64. XOR slot swizzle (r5-verified 0-conflict).
template <int MODE, typename OT>
__device__ __forceinline__ void gemm256(const u16* __restrict__ A, const u16* __restrict__ W,
                                        const float* __restrict__ bias, OT* __restrict__ out,
                                        float scale, int M, u16* lds, int m0, int n0) {
  constexpr int K = 1280;
  constexpr int NT = 20;                        // K / 64
  const int tid = threadIdx.x, wid = tid >> 6, lane = tid & 63;
  const int lm = lane & 15, quad = lane >> 4;
  const int wr = wid >> 1, wc = wid & 1;        // 4M x 2N waves

  f32x4 acc[4][4] = {};

  // staging geometry: 512 threads x 16B = 8KB per glds inst (64 rows of 128B).
  // A tile = 4 insts, B tile = 2. Pre-swizzled GLOBAL col, linear LDS dest.
  const int srow = tid >> 3, sslot = tid & 7;   // row-in-inst [0,64), slot [0,8)
  const int scol = (sslot ^ (srow & 7)) * 8;
  int r0 = m0 + srow;       r0 = r0 < M ? r0 : M - 1;
  int r1 = m0 + 64 + srow;  r1 = r1 < M ? r1 : M - 1;
  int r2 = m0 + 128 + srow; r2 = r2 < M ? r2 : M - 1;
  int r3 = m0 + 192 + srow; r3 = r3 < M ? r3 : M - 1;
  const u16* a0 = A + (size_t)r0 * K + scol;
  const u16* a1 = A + (size_t)r1 * K + scol;
  const u16* a2 = A + (size_t)r2 * K + scol;
  const u16* a3 = A + (size_t)r3 * K + scol;
  const u16* w0 = W + (size_t)(n0 + srow) * K + scol;
  const u16* w1 = W + (size_t)(n0 + 64 + srow) * K + scol;
  const int wdst = wid * 512;                   // wave-uniform: 8 rows x 64 u16

  // buffer b at b*24576 u16 (A at +0: 16384 u16, B at +16384: 8192 u16)
  auto stage_p = [&](int t, int bsel2, int p) {
    u16* bb = lds + bsel2 * 24576;
    const int kt = t * 64;
    if (p == 0) {
      glds16(a0 + kt, bb + wdst);
      glds16(a1 + kt, bb + 4096 + wdst);
      glds16(a2 + kt, bb + 8192 + wdst);
    } else {
      glds16(a3 + kt, bb + 12288 + wdst);
      glds16(w0 + kt, bb + 16384 + wdst);
      glds16(w1 + kt, bb + 20480 + wdst);
    }
  };

  // prologue: tiles 0,1 fully issued; wait for tile 0 only (6 newest stay in flight)
  stage_p(0, 0, 0); stage_p(0, 0, 1);
  stage_p(1, 1, 0); stage_p(1, 1, 1);
  asm volatile("s_waitcnt vmcnt(6)" ::: "memory");
  __builtin_amdgcn_s_barrier();

  int bsel = 0;
  for (int t = 0; t < NT; ++t) {
    const u16* Ab = lds + bsel * 24576;
    const u16* Bb = Ab + 16384;
    const int b2 = bsel >= 1 ? bsel - 1 : 2;    // (bsel+2)%3
    const bool pf = (t + 2) < NT;
#pragma unroll
    for (int kk = 0; kk < 2; ++kk) {
      const int co = ((kk * 4 + quad) ^ (lm & 7)) * 8;
      bf16x8 af[4], bfr[4];
#pragma unroll
      for (int i = 0; i < 4; ++i)
        af[i] = *(const bf16x8*)(Ab + (wr * 64 + i * 16 + lm) * 64 + co);
#pragma unroll
      for (int j = 0; j < 4; ++j)
        bfr[j] = *(const bf16x8*)(Bb + (wc * 64 + j * 16 + lm) * 64 + co);
      if (pf) stage_p(t + 2, b2, kk);           // 3 glds into tile-(t+2) buffer
      __builtin_amdgcn_sched_barrier(0);        // pin reads+stage before the barrier
      __builtin_amdgcn_s_barrier();
      __builtin_amdgcn_s_setprio(1);
#pragma unroll
      for (int i = 0; i < 4; ++i)
#pragma unroll
        for (int j = 0; j < 4; ++j)
          acc[i][j] = __builtin_amdgcn_mfma_f32_16x16x32_bf16(af[i], bfr[j], acc[i][j], 0, 0, 0);
      __builtin_amdgcn_s_setprio(0);
      __builtin_amdgcn_s_barrier();
    }
    if (t + 1 < NT) {                           // boundary: tile t+1 must be resident
      if (pf) asm volatile("s_waitcnt vmcnt(6)" ::: "memory");
      else    asm volatile("s_waitcnt vmcnt(0)" ::: "memory");
      __builtin_amdgcn_s_barrier();
    }
    bsel = bsel == 2 ? 0 : bsel + 1;
  }

#pragma unroll
  for (int j = 0; j < 4; ++j) {
    const int col = n0 + wc * 64 + j * 16 + lm;
    const float bb = bias ? bias[col] : 0.0f;
    const int hh = col >> 6, dd = col & 63;
#pragma unroll
    for (int i = 0; i < 4; ++i) {
      const int row0 = m0 + wr * 64 + i * 16 + quad * 4;
#pragma unroll
      for (int r = 0; r < 4; ++r) {
        const int row = row0 + r;
        if (row < M) {
          const float v = (acc[i][j][r] + bb) * scale;
          if (MODE == 0) {
            out[(size_t)row * 1280 + col] = (OT)v;
          } else {
            const int bidx = row / 1500, s = row - bidx * 1500;
            if (MODE == 1)
              out[((size_t)(bidx * 20 + hh) * 1500 + s) * 64 + dd] = (OT)f2bf(v);
            else
              out[((size_t)(bidx * 20 + hh) * 64 + dd) * 1504 + s] = (OT)f2bf(v);
          }
        }
      }
    }
  }
}

// XCD-banded bijective remap: 24 row-panels / 8 XCDs = 3 each (1.97MB A-band, L2-fit);
// x innermost so weight panels stream while the A-band is L2-hot.
__global__ __launch_bounds__(512, 2) void qkv_kernel(const u16* __restrict__ hs,
    const u16* __restrict__ Wq, const float* __restrict__ bq, const u16* __restrict__ Wk,
    const u16* __restrict__ Wv, const float* __restrict__ bv,
    u16* __restrict__ q_ws, u16* __restrict__ k_ws, u16* __restrict__ vt_ws, int M) {
  __shared__ __align__(16) u16 lds[3 * 24576];  // 144KB: 3-stage pipeline
  const int n = blockIdx.x;                     // grid = 720 (8 XCD * 90)
  const int xcd = n & 7, j = n >> 3;            // j in [0,90)
  const int x = xcd * 3 + (j % 3);              // [0,24)
  const int yz = j / 3;                         // [0,30)
  const int y = yz % 10, z = yz / 10;
  const int m0 = x * 256, n0 = y * 128;
  if (z == 0)
    gemm256<1, u16>(hs, Wq, bq, q_ws, 0.18033688f, M, lds, m0, n0);  // 0.125*log2(e)
  else if (z == 1)
    gemm256<1, u16>(hs, Wk, nullptr, k_ws, 1.0f, M, lds, m0, n0);
  else
    gemm256<2, u16>(hs, Wv, bv, vt_ws, 1.0f, M, lds, m0, n0);
}

__global__ __launch_bounds__(512, 2) void out_kernel(const u16* __restrict__ attn,
    const u16* __restrict__ Wo, const float* __restrict__ bo, float* __restrict__ out, int M) {
  __shared__ __align__(16) u16 lds[3 * 24576];
  const int n = blockIdx.x;                     // grid = 240 (8 XCD * 30)
  const int xcd = n & 7, j = n >> 3;            // j in [0,30)
  const int x = xcd * 3 + (j % 3);              // [0,24)
  const int y = j / 3;                          // [0,10)
  gemm256<0, float>(attn, Wo, bo, out, 1.0f, M, lds, x * 256, y * 128);
}

// ---------------- Flash attention: swapped QK^T, in-register softmax/P ----------------
// (unchanged from r5 — steady-state no longer the pacing kernel)
__global__ __launch_bounds__(256, 4) void attn_kernel(const u16* __restrict__ Qm,
    const u16* __restrict__ Km, const u16* __restrict__ Vtm, u16* __restrict__ Out) {
  const int qt = blockIdx.x, h = blockIdx.y, b = blockIdx.z;
  const int bh = b * 20 + h;
  const int tid = threadIdx.x, wid = tid >> 6, lane = tid & 63;
  const int lm = lane & 15, quad = lane >> 4;

  __shared__ __align__(16) u16 Ks[2][64 * 64];    // [kpos][d], XOR-chunk swizzled
  __shared__ __align__(16) u16 Vts[2][64 * 64];   // [d][kpos], swizzled

  const u16* Qb = Qm + (size_t)bh * (1500 * 64);
  const u16* Kb = Km + (size_t)bh * (1500 * 64);
  const u16* Vb = Vtm + (size_t)bh * (64 * 1504);

  bf16x8 qf[2][2];
#pragma unroll
  for (int g = 0; g < 2; ++g) {
    int qrow = qt * 128 + wid * 32 + g * 16 + lm;
    if (qrow > 1499) qrow = 1499;                 // dup rows masked at store
    qf[g][0] = *(const bf16x8*)(Qb + (size_t)qrow * 64 + quad * 8);
    qf[g][1] = *(const bf16x8*)(Qb + (size_t)qrow * 64 + 32 + quad * 8);
  }

  const int rr = tid >> 3, cc = tid & 7;
  const int s0 = (cc ^ (rr & 7)) * 8;             // (rr+32)&7 == rr&7

  auto stage = [&](int kt, int bi) {
    int kr0 = kt + rr;      if (kr0 > 1499) kr0 = 1499;
    int kr1 = kt + rr + 32; if (kr1 > 1499) kr1 = 1499;
    int vcol = kt + s0;     if (vcol > 1496) vcol = 1496;   // keep V reads in-bounds/finite
    u16* lk = &Ks[bi][0] + wid * 512;
    u16* lv = &Vts[bi][0] + wid * 512;
    glds16(Kb + (size_t)kr0 * 64 + s0, lk);
    glds16(Kb + (size_t)kr1 * 64 + s0, lk + 2048);
    glds16(Vb + (size_t)rr * 1504 + vcol, lv);
    glds16(Vb + (size_t)(rr + 32) * 1504 + vcol, lv + 2048);
  };

  stage(0, 0);
  __syncthreads();

  float m_s[2] = {-1e30f, -1e30f};
  float l_s[2] = {0.f, 0.f};
  f32x4 o_acc[2][4] = {};

  for (int it = 0; it < 24; ++it) {
    const int cur = it & 1;
    if (it + 1 < 24) stage((it + 1) * 64, cur ^ 1);   // async into other buffer

    f32x4 st[2][4] = {};
    __builtin_amdgcn_s_setprio(1);
#pragma unroll
    for (int kk = 0; kk < 2; ++kk) {
#pragma unroll
      for (int t = 0; t < 4; ++t) {
        const bf16x8 kf = *(const bf16x8*)(&Ks[cur][(t * 16 + lm) * 64 + (((kk * 4 + quad) ^ (lm & 7)) * 8)]);
        st[0][t] = __builtin_amdgcn_mfma_f32_16x16x32_bf16(kf, qf[0][kk], st[0][t], 0, 0, 0);
        st[1][t] = __builtin_amdgcn_mfma_f32_16x16x32_bf16(kf, qf[1][kk], st[1][t], 0, 0, 0);
      }
    }
    __builtin_amdgcn_s_setprio(0);
    if (it == 23) {                               // ragged tile: kpos = 1472 + t*16+quad*4+r
#pragma unroll
      for (int t = 0; t < 4; ++t)
#pragma unroll
        for (int r = 0; r < 4; ++r)
          if (t * 16 + quad * 4 + r >= 28) { st[0][t][r] = -1e30f; st[1][t][r] = -1e30f; }
    }

    bf16x8 pf[2][2];
#pragma unroll
    for (int g = 0; g < 2; ++g) {
      float a0 = fmaxf(fmaxf(st[g][0][0], st[g][0][1]), fmaxf(st[g][0][2], st[g][0][3]));
      float a1 = fmaxf(fmaxf(st[g][1][0], st[g][1][1]), fmaxf(st[g][1][2], st[g][1][3]));
      float a2 = fmaxf(fmaxf(st[g][2][0], st[g][2][1]), fmaxf(st[g][2][2], st[g][2][3]));
      float a3 = fmaxf(fmaxf(st[g][3][0], st[g][3][1]), fmaxf(st[g][3][2], st[g][3][3]));
      float rm = xquad_max(fmaxf(fmaxf(a0, a1), fmaxf(a2, a3)));

      // T13 defer-max (THR=8, exp2 domain -> P<=256). Wave-uniform branch.
      if (!__all(rm - m_s[g] <= 8.0f)) {
        const float mn = fmaxf(m_s[g], rm);
        const float al = exp2f(m_s[g] - mn);      // first iter: exp2(-inf) = 0
        m_s[g] = mn;
        l_s[g] *= al;
#pragma unroll
        for (int r = 0; r < 4; ++r) {
          const float ao = __shfl(al, quad * 4 + r);
#pragma unroll
          for (int t = 0; t < 4; ++t) o_acc[g][t][r] *= ao;
        }
      }
      const float mn = m_s[g];

      float rs = 0.f;
      unsigned A[4], B[4];
#pragma unroll
      for (int t = 0; t < 4; ++t) {
        const float p0 = exp2f(st[g][t][0] - mn);
        const float p1 = exp2f(st[g][t][1] - mn);
        const float p2 = exp2f(st[g][t][2] - mn);
        const float p3 = exp2f(st[g][t][3] - mn);
        rs += (p0 + p1) + (p2 + p3);
        A[t] = cvt_pk_bf16(p0, p1);
        B[t] = cvt_pk_bf16(p2, p3);
      }
      l_s[g] += xquad_sum(rs);                    // off the PV critical path

#pragma unroll
      for (int kk = 0; kk < 2; ++kk) {
        unsigned x0 = A[2 * kk], x1 = A[2 * kk + 1];
        quad_swap(x0, x1);                        // -> dwords 0 (k+0,1) and 2 (k+4,5)
        unsigned y0 = B[2 * kk], y1 = B[2 * kk + 1];
        quad_swap(y0, y1);                        // -> dwords 1 (k+2,3) and 3 (k+6,7)
        u32x4 w; w[0] = x0; w[1] = y0; w[2] = x1; w[3] = y1;
        pf[g][kk] = __builtin_bit_cast(bf16x8, w);
      }
    }

    // O += P V
    __builtin_amdgcn_s_setprio(1);
#pragma unroll
    for (int kk = 0; kk < 2; ++kk) {
#pragma unroll
      for (int t = 0; t < 4; ++t) {
        const bf16x8 vf = *(const bf16x8*)(&Vts[cur][(t * 16 + lm) * 64 + (((kk * 4 + quad) ^ (lm & 7)) * 8)]);
        o_acc[0][t] = __builtin_amdgcn_mfma_f32_16x16x32_bf16(pf[0][kk], vf, o_acc[0][t], 0, 0, 0);
        o_acc[1][t] = __builtin_amdgcn_mfma_f32_16x16x32_bf16(pf[1][kk], vf, o_acc[1][t], 0, 0, 0);
      }
    }
    __builtin_amdgcn_s_setprio(0);

    __syncthreads();                              // drains glds (vmcnt) + orders dbuf swap
  }

#pragma unroll
  for (int g = 0; g < 2; ++g)
#pragma unroll
    for (int r = 0; r < 4; ++r) {
      const float lr = __shfl(l_s[g], quad * 4 + r);
      const float inv = 1.0f / lr;
      const int qg = qt * 128 + wid * 32 + g * 16 + quad * 4 + r;
      if (qg < 1500) {
#pragma unroll
        for (int t = 0; t < 4; ++t)
          Out[((size_t)(b * 1500 + qg)) * 1280 + h * 64 + t * 16 + lm] =
              f2bf(o_acc[g][t][r] * inv);
      }
    }
}

extern "C" void kernel_launch(void* const* d_in, const int* in_sizes, int n_in,
                              void* d_out, int out_size, void* d_ws, size_t ws_size,
                              hipStream_t stream) {
  const float* hs = (const float*)d_in[0];
  const float* Wq = (const float*)d_in[2];
  const float* bq = (const float*)d_in[3];
  const float* Wk = (const float*)d_in[4];
  const float* Wv = (const float*)d_in[5];
  const float* bv = (const float*)d_in[6];
  const float* Wo = (const float*)d_in[7];
  const float* bo = (const float*)d_in[8];

  u16* cvt     = (u16*)d_ws;
  u16* hs_bf   = cvt;                          // [6000,1280]
  u16* Wq_bf   = cvt + 7680000;
  u16* Wk_bf   = cvt + 9318400;
  u16* Wv_bf   = cvt + 10956800;
  u16* Wo_bf   = cvt + 12595200;
  u16* q_ws    = cvt + 14233600;               // [4,20,1500,64]
  u16* k_ws    = q_ws + 7680000;
  u16* vt_ws   = k_ws + 7680000;               // [4,20,64,1504] (+64 pad)
  u16* attn_ws = vt_ws + 7700480 + 64;         // [6000,1280]
  const int M = 6000;

  hipLaunchKernelGGL(cvt_kernel, dim3(2048), dim3(256), 0, stream,
                     (const float4*)hs, (const float4*)Wq, (const float4*)Wk,
                     (const float4*)Wv, (const float4*)Wo, cvt);
  hipLaunchKernelGGL(qkv_kernel, dim3(720), dim3(512), 0, stream,
                     hs_bf, Wq_bf, bq, Wk_bf, Wv_bf, bv, q_ws, k_ws, vt_ws, M);
  hipLaunchKernelGGL(attn_kernel, dim3(12, 20, 4), dim3(256), 0, stream,
                     q_ws, k_ws, vt_ws, attn_ws);
  hipLaunchKernelGGL(out_kernel, dim3(240), dim3(512), 0, stream,
                     attn_ws, Wo_bf, bo, (float*)d_out, M);
}

// Round 7
// 321.769 us; speedup vs baseline: 1.1851x; 1.1036x over previous
//
#include <hip/hip_runtime.h>

typedef unsigned short u16;
using bf16x8 = __attribute__((ext_vector_type(8))) __bf16;
using f32x4  = __attribute__((ext_vector_type(4))) float;
using u32x2  = __attribute__((ext_vector_type(2))) unsigned;
using u32x4  = __attribute__((ext_vector_type(4))) unsigned;

#define AS1 __attribute__((address_space(1)))
#define AS3 __attribute__((address_space(3)))

__device__ __forceinline__ void glds16(const u16* g, u16* l) {
  __builtin_amdgcn_global_load_lds((AS1 void*)const_cast<u16*>(g), (AS3 void*)l, 16, 0, 0);
}

__device__ __forceinline__ u16 f2bf(float f) {
  unsigned u = __float_as_uint(f);
  u += 0x7FFFu + ((u >> 16) & 1u);
  return (u16)(u >> 16);
}
__device__ __forceinline__ ushort4 cvt4(float4 v) {
  return make_ushort4(f2bf(v.x), f2bf(v.y), f2bf(v.z), f2bf(v.w));
}

__device__ __forceinline__ unsigned cvt_pk_bf16(float lo, float hi) {
  unsigned r;
  asm("v_cvt_pk_bf16_f32 %0, %1, %2" : "=v"(r) : "v"(lo), "v"(hi));
  return r;
}

// raw v_exp_f32 (1 inst, 1ulp) vs libm exp2f's denormal-guarded ~5-inst lowering.
// Inputs here are <= 0 and results feed bf16 rounding -> denormal fixup is useless.
#if __has_builtin(__builtin_amdgcn_exp2f)
__device__ __forceinline__ float fexp2(float x) { return __builtin_amdgcn_exp2f(x); }
#else
__device__ __forceinline__ float fexp2(float x) { return exp2f(x); }
#endif

// full quad exchange via permlane32_swap + permlane16_swap (r0 derivation):
// yields PV A-frag dword pairs from per-lane packed P values.
__device__ __forceinline__ void quad_swap(unsigned& x, unsigned& y) {
  u32x2 a = __builtin_amdgcn_permlane32_swap(x, y, false, false);
  u32x2 b = __builtin_amdgcn_permlane16_swap(a[0], a[1], false, false);
  x = b[0];
  y = b[1];
}

// cross-quad reductions via permlane swaps (VALU) instead of DS round-trips.
__device__ __forceinline__ float xquad_max(float x) {
  u32x2 a = __builtin_amdgcn_permlane16_swap(__float_as_uint(x), __float_as_uint(x), false, false);
  float y = fmaxf(__uint_as_float(a[0]), __uint_as_float(a[1]));
  u32x2 b = __builtin_amdgcn_permlane32_swap(__float_as_uint(y), __float_as_uint(y), false, false);
  return fmaxf(__uint_as_float(b[0]), __uint_as_float(b[1]));
}
__device__ __forceinline__ float xquad_sum(float x) {
  u32x2 a = __builtin_amdgcn_permlane16_swap(__float_as_uint(x), __float_as_uint(x), false, false);
  float y = __uint_as_float(a[0]) + __uint_as_float(a[1]);
  u32x2 b = __builtin_amdgcn_permlane32_swap(__float_as_uint(y), __float_as_uint(y), false, false);
  return __uint_as_float(b[0]) + __uint_as_float(b[1]);
}

// ---------------- one-shot fp32 -> bf16 conversion ----------------
__global__ __launch_bounds__(256) void cvt_kernel(const float4* __restrict__ hs,
    const float4* __restrict__ wq, const float4* __restrict__ wk,
    const float4* __restrict__ wv, const float4* __restrict__ wo, u16* __restrict__ dst) {
  const long stride = (long)gridDim.x * blockDim.x;
  for (long i = (long)blockIdx.x * blockDim.x + threadIdx.x; i < 3558400; i += stride) {
    const float4* src; long rel; u16* d;
    if (i < 1920000)      { src = hs; rel = i;           d = dst; }
    else if (i < 2329600) { src = wq; rel = i - 1920000; d = dst + 7680000; }
    else if (i < 2739200) { src = wk; rel = i - 2329600; d = dst + 9318400; }
    else if (i < 3148800) { src = wv; rel = i - 2739200; d = dst + 10956800; }
    else                  { src = wo; rel = i - 3148800; d = dst + 12595200; }
    *(ushort4*)(d + rel * 4) = cvt4(src[rel]);
  }
}

// ---------------- bf16 GEMM: 256x128 tile, BK=64, 3-stage counted-vmcnt pipeline ----
// (unchanged from r6 — verified win)
template <int MODE, typename OT>
__device__ __forceinline__ void gemm256(const u16* __restrict__ A, const u16* __restrict__ W,
                                        const float* __restrict__ bias, OT* __restrict__ out,
                                        float scale, int M, u16* lds, int m0, int n0) {
  constexpr int K = 1280;
  constexpr int NT = 20;                        // K / 64
  const int tid = threadIdx.x, wid = tid >> 6, lane = tid & 63;
  const int lm = lane & 15, quad = lane >> 4;
  const int wr = wid >> 1, wc = wid & 1;        // 4M x 2N waves

  f32x4 acc[4][4] = {};

  const int srow = tid >> 3, sslot = tid & 7;   // row-in-inst [0,64), slot [0,8)
  const int scol = (sslot ^ (srow & 7)) * 8;
  int r0 = m0 + srow;       r0 = r0 < M ? r0 : M - 1;
  int r1 = m0 + 64 + srow;  r1 = r1 < M ? r1 : M - 1;
  int r2 = m0 + 128 + srow; r2 = r2 < M ? r2 : M - 1;
  int r3 = m0 + 192 + srow; r3 = r3 < M ? r3 : M - 1;
  const u16* a0 = A + (size_t)r0 * K + scol;
  const u16* a1 = A + (size_t)r1 * K + scol;
  const u16* a2 = A + (size_t)r2 * K + scol;
  const u16* a3 = A + (size_t)r3 * K + scol;
  const u16* w0 = W + (size_t)(n0 + srow) * K + scol;
  const u16* w1 = W + (size_t)(n0 + 64 + srow) * K + scol;
  const int wdst = wid * 512;                   // wave-uniform: 8 rows x 64 u16

  auto stage_p = [&](int t, int bsel2, int p) {
    u16* bb = lds + bsel2 * 24576;
    const int kt = t * 64;
    if (p == 0) {
      glds16(a0 + kt, bb + wdst);
      glds16(a1 + kt, bb + 4096 + wdst);
      glds16(a2 + kt, bb + 8192 + wdst);
    } else {
      glds16(a3 + kt, bb + 12288 + wdst);
      glds16(w0 + kt, bb + 16384 + wdst);
      glds16(w1 + kt, bb + 20480 + wdst);
    }
  };

  stage_p(0, 0, 0); stage_p(0, 0, 1);
  stage_p(1, 1, 0); stage_p(1, 1, 1);
  asm volatile("s_waitcnt vmcnt(6)" ::: "memory");
  __builtin_amdgcn_s_barrier();

  int bsel = 0;
  for (int t = 0; t < NT; ++t) {
    const u16* Ab = lds + bsel * 24576;
    const u16* Bb = Ab + 16384;
    const int b2 = bsel >= 1 ? bsel - 1 : 2;    // (bsel+2)%3
    const bool pf = (t + 2) < NT;
#pragma unroll
    for (int kk = 0; kk < 2; ++kk) {
      const int co = ((kk * 4 + quad) ^ (lm & 7)) * 8;
      bf16x8 af[4], bfr[4];
#pragma unroll
      for (int i = 0; i < 4; ++i)
        af[i] = *(const bf16x8*)(Ab + (wr * 64 + i * 16 + lm) * 64 + co);
#pragma unroll
      for (int j = 0; j < 4; ++j)
        bfr[j] = *(const bf16x8*)(Bb + (wc * 64 + j * 16 + lm) * 64 + co);
      if (pf) stage_p(t + 2, b2, kk);           // 3 glds into tile-(t+2) buffer
      __builtin_amdgcn_sched_barrier(0);        // pin reads+stage before the barrier
      __builtin_amdgcn_s_barrier();
      __builtin_amdgcn_s_setprio(1);
#pragma unroll
      for (int i = 0; i < 4; ++i)
#pragma unroll
        for (int j = 0; j < 4; ++j)
          acc[i][j] = __builtin_amdgcn_mfma_f32_16x16x32_bf16(af[i], bfr[j], acc[i][j], 0, 0, 0);
      __builtin_amdgcn_s_setprio(0);
      __builtin_amdgcn_s_barrier();
    }
    if (t + 1 < NT) {                           // boundary: tile t+1 must be resident
      if (pf) asm volatile("s_waitcnt vmcnt(6)" ::: "memory");
      else    asm volatile("s_waitcnt vmcnt(0)" ::: "memory");
      __builtin_amdgcn_s_barrier();
    }
    bsel = bsel == 2 ? 0 : bsel + 1;
  }

#pragma unroll
  for (int j = 0; j < 4; ++j) {
    const int col = n0 + wc * 64 + j * 16 + lm;
    const float bb = bias ? bias[col] : 0.0f;
    const int hh = col >> 6, dd = col & 63;
#pragma unroll
    for (int i = 0; i < 4; ++i) {
      const int row0 = m0 + wr * 64 + i * 16 + quad * 4;
#pragma unroll
      for (int r = 0; r < 4; ++r) {
        const int row = row0 + r;
        if (row < M) {
          const float v = (acc[i][j][r] + bb) * scale;
          if (MODE == 0) {
            out[(size_t)row * 1280 + col] = (OT)v;
          } else {
            const int bidx = row / 1500, s = row - bidx * 1500;
            if (MODE == 1)
              out[((size_t)(bidx * 20 + hh) * 1500 + s) * 64 + dd] = (OT)f2bf(v);
            else
              out[((size_t)(bidx * 20 + hh) * 64 + dd) * 1504 + s] = (OT)f2bf(v);
          }
        }
      }
    }
  }
}

__global__ __launch_bounds__(512, 2) void qkv_kernel(const u16* __restrict__ hs,
    const u16* __restrict__ Wq, const float* __restrict__ bq, const u16* __restrict__ Wk,
    const u16* __restrict__ Wv, const float* __restrict__ bv,
    u16* __restrict__ q_ws, u16* __restrict__ k_ws, u16* __restrict__ vt_ws, int M) {
  __shared__ __align__(16) u16 lds[3 * 24576];  // 144KB: 3-stage pipeline
  const int n = blockIdx.x;                     // grid = 720 (8 XCD * 90)
  const int xcd = n & 7, j = n >> 3;            // j in [0,90)
  const int x = xcd * 3 + (j % 3);              // [0,24)
  const int yz = j / 3;                         // [0,30)
  const int y = yz % 10, z = yz / 10;
  const int m0 = x * 256, n0 = y * 128;
  if (z == 0)
    gemm256<1, u16>(hs, Wq, bq, q_ws, 0.18033688f, M, lds, m0, n0);  // 0.125*log2(e)
  else if (z == 1)
    gemm256<1, u16>(hs, Wk, nullptr, k_ws, 1.0f, M, lds, m0, n0);
  else
    gemm256<2, u16>(hs, Wv, bv, vt_ws, 1.0f, M, lds, m0, n0);
}

__global__ __launch_bounds__(512, 2) void out_kernel(const u16* __restrict__ attn,
    const u16* __restrict__ Wo, const float* __restrict__ bo, float* __restrict__ out, int M) {
  __shared__ __align__(16) u16 lds[3 * 24576];
  const int n = blockIdx.x;                     // grid = 240 (8 XCD * 30)
  const int xcd = n & 7, j = n >> 3;            // j in [0,30)
  const int x = xcd * 3 + (j % 3);              // [0,24)
  const int y = j / 3;                          // [0,10)
  gemm256<0, float>(attn, Wo, bo, out, 1.0f, M, lds, x * 256, y * 128);
}

// ---------------- Flash attention: 3-stage counted-vmcnt K/V pipeline ----------------
// Q,K: [b,h,1500,64] bf16 (Q pre-scaled by 0.125*log2e); Vt: [b,h,64,1504] bf16.
// r7: (1) 3 LDS stages (16KB each: K 8KB + V 8KB), stage tile t+2 at iter top,
// boundary s_waitcnt vmcnt(4) + raw s_barrier — never vmcnt(0) in loop (T4).
// WAR safe: tile t+2's buffer was last read in iter t-1, whose reads completed
// before the boundary barrier these glds follow. (2) raw v_exp_f32 via fexp2.
// (3) XCD-banded bh mapping: all 12 q-tiles of a (b,h) on one XCD -> K/V L2 reuse.
__global__ __launch_bounds__(256, 3) void attn_kernel(const u16* __restrict__ Qm,
    const u16* __restrict__ Km, const u16* __restrict__ Vtm, u16* __restrict__ Out) {
  const int n = blockIdx.x;                     // grid = 960 (8 XCD * 120)
  const int xcd = n & 7, j = n >> 3;            // j in [0,120)
  const int bh = xcd * 10 + (j % 10);           // 10 bh per XCD (bijective)
  const int qt = j / 10;                        // [0,12)
  const int b = bh / 20, h = bh % 20;
  const int tid = threadIdx.x, wid = tid >> 6, lane = tid & 63;
  const int lm = lane & 15, quad = lane >> 4;

  __shared__ __align__(16) u16 lds[3 * 8192];   // 48KB: 3 stages x {K 4096, V 4096} u16

  const u16* Qb = Qm + (size_t)bh * (1500 * 64);
  const u16* Kb = Km + (size_t)bh * (1500 * 64);
  const u16* Vb = Vtm + (size_t)bh * (64 * 1504);

  bf16x8 qf[2][2];
#pragma unroll
  for (int g = 0; g < 2; ++g) {
    int qrow = qt * 128 + wid * 32 + g * 16 + lm;
    if (qrow > 1499) qrow = 1499;                 // dup rows masked at store
    qf[g][0] = *(const bf16x8*)(Qb + (size_t)qrow * 64 + quad * 8);
    qf[g][1] = *(const bf16x8*)(Qb + (size_t)qrow * 64 + 32 + quad * 8);
  }

  // staging: thread (rr, cc) stages 16B chunks; swizzle on the GLOBAL side,
  // LDS dest linear (global_load_lds requirement).
  const int rr = tid >> 3, cc = tid & 7;
  const int s0 = (cc ^ (rr & 7)) * 8;             // (rr+32)&7 == rr&7

  auto stage = [&](int kt, int bi) {
    int kr0 = kt + rr;      if (kr0 > 1499) kr0 = 1499;
    int kr1 = kt + rr + 32; if (kr1 > 1499) kr1 = 1499;
    int vcol = kt + s0;     if (vcol > 1496) vcol = 1496;   // keep V reads in-bounds/finite
    u16* lk = lds + bi * 8192 + wid * 512;
    u16* lv = lk + 4096;
    glds16(Kb + (size_t)kr0 * 64 + s0, lk);
    glds16(Kb + (size_t)kr1 * 64 + s0, lk + 2048);
    glds16(Vb + (size_t)rr * 1504 + vcol, lv);
    glds16(Vb + (size_t)(rr + 32) * 1504 + vcol, lv + 2048);
  };

  // prologue: tiles 0,1; wait tile 0 only (tile 1's 4 loads stay in flight)
  stage(0, 0);
  stage(64, 1);
  asm volatile("s_waitcnt vmcnt(4)" ::: "memory");
  __builtin_amdgcn_s_barrier();

  float m_s[2] = {-1e30f, -1e30f};
  float l_s[2] = {0.f, 0.f};
  f32x4 o_acc[2][4] = {};

  int bsel = 0;
  for (int it = 0; it < 24; ++it) {
    const u16* Kc = lds + bsel * 8192;
    const u16* Vc = Kc + 4096;
    if (it + 2 < 24) stage((it + 2) * 64, bsel >= 1 ? bsel - 1 : 2);  // (bsel+2)%3

    // S^T = K Q^T : st[g][t] lane holds q-row lm, kpos = t*16 + quad*4 + r
    f32x4 st[2][4] = {};
    __builtin_amdgcn_s_setprio(1);
#pragma unroll
    for (int kk = 0; kk < 2; ++kk) {
#pragma unroll
      for (int t = 0; t < 4; ++t) {
        const bf16x8 kf = *(const bf16x8*)(Kc + (t * 16 + lm) * 64 + (((kk * 4 + quad) ^ (lm & 7)) * 8));
        st[0][t] = __builtin_amdgcn_mfma_f32_16x16x32_bf16(kf, qf[0][kk], st[0][t], 0, 0, 0);
        st[1][t] = __builtin_amdgcn_mfma_f32_16x16x32_bf16(kf, qf[1][kk], st[1][t], 0, 0, 0);
      }
    }
    __builtin_amdgcn_s_setprio(0);
    if (it == 23) {                               // ragged tile: kpos = 1472 + t*16+quad*4+r
#pragma unroll
      for (int t = 0; t < 4; ++t)
#pragma unroll
        for (int r = 0; r < 4; ++r)
          if (t * 16 + quad * 4 + r >= 28) { st[0][t][r] = -1e30f; st[1][t][r] = -1e30f; }
    }

    bf16x8 pf[2][2];
#pragma unroll
    for (int g = 0; g < 2; ++g) {
      float a0 = fmaxf(fmaxf(st[g][0][0], st[g][0][1]), fmaxf(st[g][0][2], st[g][0][3]));
      float a1 = fmaxf(fmaxf(st[g][1][0], st[g][1][1]), fmaxf(st[g][1][2], st[g][1][3]));
      float a2 = fmaxf(fmaxf(st[g][2][0], st[g][2][1]), fmaxf(st[g][2][2], st[g][2][3]));
      float a3 = fmaxf(fmaxf(st[g][3][0], st[g][3][1]), fmaxf(st[g][3][2], st[g][3][3]));
      float rm = xquad_max(fmaxf(fmaxf(a0, a1), fmaxf(a2, a3)));

      // T13 defer-max (THR=8, exp2 domain -> P<=256). Wave-uniform branch.
      if (!__all(rm - m_s[g] <= 8.0f)) {
        const float mn = fmaxf(m_s[g], rm);
        const float al = fexp2(m_s[g] - mn);      // first iter: fexp2(-1e30) = 0
        m_s[g] = mn;
        l_s[g] *= al;
#pragma unroll
        for (int r = 0; r < 4; ++r) {
          const float ao = __shfl(al, quad * 4 + r);
#pragma unroll
          for (int t = 0; t < 4; ++t) o_acc[g][t][r] *= ao;
        }
      }
      const float mn = m_s[g];

      float rs = 0.f;
      unsigned A[4], B[4];
#pragma unroll
      for (int t = 0; t < 4; ++t) {
        const float p0 = fexp2(st[g][t][0] - mn);
        const float p1 = fexp2(st[g][t][1] - mn);
        const float p2 = fexp2(st[g][t][2] - mn);
        const float p3 = fexp2(st[g][t][3] - mn);
        rs += (p0 + p1) + (p2 + p3);
        A[t] = cvt_pk_bf16(p0, p1);
        B[t] = cvt_pk_bf16(p2, p3);
      }
      l_s[g] += xquad_sum(rs);                    // off the PV critical path

#pragma unroll
      for (int kk = 0; kk < 2; ++kk) {
        unsigned x0 = A[2 * kk], x1 = A[2 * kk + 1];
        quad_swap(x0, x1);                        // -> dwords 0 (k+0,1) and 2 (k+4,5)
        unsigned y0 = B[2 * kk], y1 = B[2 * kk + 1];
        quad_swap(y0, y1);                        // -> dwords 1 (k+2,3) and 3 (k+6,7)
        u32x4 w; w[0] = x0; w[1] = y0; w[2] = x1; w[3] = y1;
        pf[g][kk] = __builtin_bit_cast(bf16x8, w);
      }
    }

    // O += P V
    __builtin_amdgcn_s_setprio(1);
#pragma unroll
    for (int kk = 0; kk < 2; ++kk) {
#pragma unroll
      for (int t = 0; t < 4; ++t) {
        const bf16x8 vf = *(const bf16x8*)(Vc + (t * 16 + lm) * 64 + (((kk * 4 + quad) ^ (lm & 7)) * 8));
        o_acc[0][t] = __builtin_amdgcn_mfma_f32_16x16x32_bf16(pf[0][kk], vf, o_acc[0][t], 0, 0, 0);
        o_acc[1][t] = __builtin_amdgcn_mfma_f32_16x16x32_bf16(pf[1][kk], vf, o_acc[1][t], 0, 0, 0);
      }
    }
    __builtin_amdgcn_s_setprio(0);

    if (it + 1 < 24) {                            // boundary: tile it+1 must be resident
      if (it + 2 < 24) asm volatile("s_waitcnt vmcnt(4)" ::: "memory");
      else             asm volatile("s_waitcnt vmcnt(0)" ::: "memory");
      __builtin_amdgcn_s_barrier();
    }
    bsel = bsel == 2 ? 0 : bsel + 1;
  }

#pragma unroll
  for (int g = 0; g < 2; ++g)
#pragma unroll
    for (int r = 0; r < 4; ++r) {
      const float lr = __shfl(l_s[g], quad * 4 + r);
      const float inv = 1.0f / lr;
      const int qg = qt * 128 + wid * 32 + g * 16 + quad * 4 + r;
      if (qg < 1500) {
#pragma unroll
        for (int t = 0; t < 4; ++t)
          Out[((size_t)(b * 1500 + qg)) * 1280 + h * 64 + t * 16 + lm] =
              f2bf(o_acc[g][t][r] * inv);
      }
    }
}

extern "C" void kernel_launch(void* const* d_in, const int* in_sizes, int n_in,
                              void* d_out, int out_size, void* d_ws, size_t ws_size,
                              hipStream_t stream) {
  const float* hs = (const float*)d_in[0];
  const float* Wq = (const float*)d_in[2];
  const float* bq = (const float*)d_in[3];
  const float* Wk = (const float*)d_in[4];
  const float* Wv = (const float*)d_in[5];
  const float* bv = (const float*)d_in[6];
  const float* Wo = (const float*)d_in[7];
  const float* bo = (const float*)d_in[8];

  u16* cvt     = (u16*)d_ws;
  u16* hs_bf   = cvt;                          // [6000,1280]
  u16* Wq_bf   = cvt + 7680000;
  u16* Wk_bf   = cvt + 9318400;
  u16* Wv_bf   = cvt + 10956800;
  u16* Wo_bf   = cvt + 12595200;
  u16* q_ws    = cvt + 14233600;               // [4,20,1500,64]
  u16* k_ws    = q_ws + 7680000;
  u16* vt_ws   = k_ws + 7680000;               // [4,20,64,1504] (+64 pad)
  u16* attn_ws = vt_ws + 7700480 + 64;         // [6000,1280]
  const int M = 6000;

  hipLaunchKernelGGL(cvt_kernel, dim3(2048), dim3(256), 0, stream,
                     (const float4*)hs, (const float4*)Wq, (const float4*)Wk,
                     (const float4*)Wv, (const float4*)Wo, cvt);
  hipLaunchKernelGGL(qkv_kernel, dim3(720), dim3(512), 0, stream,
                     hs_bf, Wq_bf, bq, Wk_bf, Wv_bf, bv, q_ws, k_ws, vt_ws, M);
  hipLaunchKernelGGL(attn_kernel, dim3(960), dim3(256), 0, stream,
                     q_ws, k_ws, vt_ws, attn_ws);
  hipLaunchKernelGGL(out_kernel, dim3(240), dim3(512), 0, stream,
                     attn_ws, Wo_bf, bo, (float*)d_out, M);
}

// Round 8
// 311.709 us; speedup vs baseline: 1.2233x; 1.0323x over previous
//
#include <hip/hip_runtime.h>

typedef unsigned short u16;
typedef unsigned long long u64;
using bf16x8 = __attribute__((ext_vector_type(8))) __bf16;
using f32x4  = __attribute__((ext_vector_type(4))) float;
using u32x2  = __attribute__((ext_vector_type(2))) unsigned;
using u32x4  = __attribute__((ext_vector_type(4))) unsigned;

#define AS1 __attribute__((address_space(1)))
#define AS3 __attribute__((address_space(3)))

__device__ __forceinline__ void glds16(const u16* g, u16* l) {
  __builtin_amdgcn_global_load_lds((AS1 void*)const_cast<u16*>(g), (AS3 void*)l, 16, 0, 0);
}

__device__ __forceinline__ u16 f2bf(float f) {
  unsigned u = __float_as_uint(f);
  u += 0x7FFFu + ((u >> 16) & 1u);
  return (u16)(u >> 16);
}
__device__ __forceinline__ ushort4 cvt4(float4 v) {
  return make_ushort4(f2bf(v.x), f2bf(v.y), f2bf(v.z), f2bf(v.w));
}

__device__ __forceinline__ unsigned cvt_pk_bf16(float lo, float hi) {
  unsigned r;
  asm("v_cvt_pk_bf16_f32 %0, %1, %2" : "=v"(r) : "v"(lo), "v"(hi));
  return r;
}

// raw v_exp_f32 (1 inst, 1ulp) vs libm exp2f's denormal-guarded ~5-inst lowering.
#if __has_builtin(__builtin_amdgcn_exp2f)
__device__ __forceinline__ float fexp2(float x) { return __builtin_amdgcn_exp2f(x); }
#else
__device__ __forceinline__ float fexp2(float x) { return exp2f(x); }
#endif

// full quad exchange via permlane32_swap + permlane16_swap (r0 derivation):
// yields PV A-frag dword pairs from per-lane packed P values.
__device__ __forceinline__ void quad_swap(unsigned& x, unsigned& y) {
  u32x2 a = __builtin_amdgcn_permlane32_swap(x, y, false, false);
  u32x2 b = __builtin_amdgcn_permlane16_swap(a[0], a[1], false, false);
  x = b[0];
  y = b[1];
}

// cross-quad reductions via permlane swaps (VALU) instead of DS round-trips.
__device__ __forceinline__ float xquad_max(float x) {
  u32x2 a = __builtin_amdgcn_permlane16_swap(__float_as_uint(x), __float_as_uint(x), false, false);
  float y = fmaxf(__uint_as_float(a[0]), __uint_as_float(a[1]));
  u32x2 b = __builtin_amdgcn_permlane32_swap(__float_as_uint(y), __float_as_uint(y), false, false);
  return fmaxf(__uint_as_float(b[0]), __uint_as_float(b[1]));
}
__device__ __forceinline__ float xquad_sum(float x) {
  u32x2 a = __builtin_amdgcn_permlane16_swap(__float_as_uint(x), __float_as_uint(x), false, false);
  float y = __uint_as_float(a[0]) + __uint_as_float(a[1]);
  u32x2 b = __builtin_amdgcn_permlane32_swap(__float_as_uint(y), __float_as_uint(y), false, false);
  return __uint_as_float(b[0]) + __uint_as_float(b[1]);
}

// ---------------- one-shot fp32 -> bf16 conversion ----------------
__global__ __launch_bounds__(256) void cvt_kernel(const float4* __restrict__ hs,
    const float4* __restrict__ wq, const float4* __restrict__ wk,
    const float4* __restrict__ wv, const float4* __restrict__ wo, u16* __restrict__ dst) {
  const long stride = (long)gridDim.x * blockDim.x;
  for (long i = (long)blockIdx.x * blockDim.x + threadIdx.x; i < 3558400; i += stride) {
    const float4* src; long rel; u16* d;
    if (i < 1920000)      { src = hs; rel = i;           d = dst; }
    else if (i < 2329600) { src = wq; rel = i - 1920000; d = dst + 7680000; }
    else if (i < 2739200) { src = wk; rel = i - 2329600; d = dst + 9318400; }
    else if (i < 3148800) { src = wv; rel = i - 2739200; d = dst + 10956800; }
    else                  { src = wo; rel = i - 3148800; d = dst + 12595200; }
    *(ushort4*)(d + rel * 4) = cvt4(src[rel]);
  }
}

// ---------------- bf16 GEMM: 256x128 tile, BK=64, 3-stage counted-vmcnt pipeline ----
// K-loop unchanged from r6 (verified). r8: MODE 2 (V^T) epilogue now goes through an
// LDS transpose: Ct[128 cols][264 pad] (ds_write_b64 packs 4 contiguous rows), then
// coalesced 16B runs along s. The old direct path scattered 64 cache lines per
// wave-store (2B at stride 3008B) ~ 32k line-transactions per block.
template <int MODE, typename OT>
__device__ __forceinline__ void gemm256(const u16* __restrict__ A, const u16* __restrict__ W,
                                        const float* __restrict__ bias, OT* __restrict__ out,
                                        float scale, int M, u16* lds, int m0, int n0) {
  constexpr int K = 1280;
  constexpr int NT = 20;                        // K / 64
  const int tid = threadIdx.x, wid = tid >> 6, lane = tid & 63;
  const int lm = lane & 15, quad = lane >> 4;
  const int wr = wid >> 1, wc = wid & 1;        // 4M x 2N waves

  f32x4 acc[4][4] = {};

  const int srow = tid >> 3, sslot = tid & 7;   // row-in-inst [0,64), slot [0,8)
  const int scol = (sslot ^ (srow & 7)) * 8;
  int r0 = m0 + srow;       r0 = r0 < M ? r0 : M - 1;
  int r1 = m0 + 64 + srow;  r1 = r1 < M ? r1 : M - 1;
  int r2 = m0 + 128 + srow; r2 = r2 < M ? r2 : M - 1;
  int r3 = m0 + 192 + srow; r3 = r3 < M ? r3 : M - 1;
  const u16* a0 = A + (size_t)r0 * K + scol;
  const u16* a1 = A + (size_t)r1 * K + scol;
  const u16* a2 = A + (size_t)r2 * K + scol;
  const u16* a3 = A + (size_t)r3 * K + scol;
  const u16* w0 = W + (size_t)(n0 + srow) * K + scol;
  const u16* w1 = W + (size_t)(n0 + 64 + srow) * K + scol;
  const int wdst = wid * 512;                   // wave-uniform: 8 rows x 64 u16

  auto stage_p = [&](int t, int bsel2, int p) {
    u16* bb = lds + bsel2 * 24576;
    const int kt = t * 64;
    if (p == 0) {
      glds16(a0 + kt, bb + wdst);
      glds16(a1 + kt, bb + 4096 + wdst);
      glds16(a2 + kt, bb + 8192 + wdst);
    } else {
      glds16(a3 + kt, bb + 12288 + wdst);
      glds16(w0 + kt, bb + 16384 + wdst);
      glds16(w1 + kt, bb + 20480 + wdst);
    }
  };

  stage_p(0, 0, 0); stage_p(0, 0, 1);
  stage_p(1, 1, 0); stage_p(1, 1, 1);
  asm volatile("s_waitcnt vmcnt(6)" ::: "memory");
  __builtin_amdgcn_s_barrier();

  int bsel = 0;
  for (int t = 0; t < NT; ++t) {
    const u16* Ab = lds + bsel * 24576;
    const u16* Bb = Ab + 16384;
    const int b2 = bsel >= 1 ? bsel - 1 : 2;    // (bsel+2)%3
    const bool pf = (t + 2) < NT;
#pragma unroll
    for (int kk = 0; kk < 2; ++kk) {
      const int co = ((kk * 4 + quad) ^ (lm & 7)) * 8;
      bf16x8 af[4], bfr[4];
#pragma unroll
      for (int i = 0; i < 4; ++i)
        af[i] = *(const bf16x8*)(Ab + (wr * 64 + i * 16 + lm) * 64 + co);
#pragma unroll
      for (int j = 0; j < 4; ++j)
        bfr[j] = *(const bf16x8*)(Bb + (wc * 64 + j * 16 + lm) * 64 + co);
      if (pf) stage_p(t + 2, b2, kk);           // 3 glds into tile-(t+2) buffer
      __builtin_amdgcn_sched_barrier(0);        // pin reads+stage before the barrier
      __builtin_amdgcn_s_barrier();
      __builtin_amdgcn_s_setprio(1);
#pragma unroll
      for (int i = 0; i < 4; ++i)
#pragma unroll
        for (int j = 0; j < 4; ++j)
          acc[i][j] = __builtin_amdgcn_mfma_f32_16x16x32_bf16(af[i], bfr[j], acc[i][j], 0, 0, 0);
      __builtin_amdgcn_s_setprio(0);
      __builtin_amdgcn_s_barrier();
    }
    if (t + 1 < NT) {                           // boundary: tile t+1 must be resident
      if (pf) asm volatile("s_waitcnt vmcnt(6)" ::: "memory");
      else    asm volatile("s_waitcnt vmcnt(0)" ::: "memory");
      __builtin_amdgcn_s_barrier();
    }
    bsel = bsel == 2 ? 0 : bsel + 1;
  }

  if constexpr (MODE == 2) {
    // -------- LDS-transpose epilogue for V^T ([dd][1504 s] output) --------
    __syncthreads();                            // K-loop LDS dead; reuse as Ct
    u16* Ct = lds;                              // [128 cols][264 pad] u16 (67.6KB)
#pragma unroll
    for (int j = 0; j < 4; ++j) {
      const int col = wc * 64 + j * 16 + lm;
      const float bb = bias ? bias[n0 + col] : 0.0f;
#pragma unroll
      for (int i = 0; i < 4; ++i) {
        const int row = wr * 64 + i * 16 + quad * 4;
        ushort4 pk;
        pk.x = f2bf((acc[i][j][0] + bb) * scale);
        pk.y = f2bf((acc[i][j][1] + bb) * scale);
        pk.z = f2bf((acc[i][j][2] + bb) * scale);
        pk.w = f2bf((acc[i][j][3] + bb) * scale);
        *(ushort4*)(Ct + col * 264 + row) = pk; // rows contiguous -> b64 pack
      }
    }
    __syncthreads();
    // 4096 chunks (128 cols x 32 row-chunks of 8); 8 per thread; coalesced along s.
#pragma unroll
    for (int k = 0; k < 8; ++k) {
      const int c8 = tid + k * 512;
      const int col = c8 >> 5, rc = c8 & 31;
      const int grow0 = m0 + rc * 8;
      if (grow0 >= M) continue;                 // clamp-duplicate rows: never stored
      const int gcol = n0 + col, hh = gcol >> 6, dd = gcol & 63;
      const u16* src = Ct + col * 264 + rc * 8;
      const int b0 = grow0 / 1500, b1 = (grow0 + 7) / 1500;
      if (b0 == b1) {                           // aligned full chunk (common case)
        const int s = grow0 - b0 * 1500;
        u16* dst = (u16*)out + ((size_t)((b0 * 20 + hh) * 64 + dd)) * 1504 + s;
        *(u64*)dst = *(const u64*)src;          // s mult of 4 -> 8B aligned
        *(u64*)(dst + 4) = *(const u64*)(src + 4);
      } else {                                  // straddles 1500-boundary (x=5,17 only)
#pragma unroll
        for (int r = 0; r < 8; ++r) {
          const int g = grow0 + r;
          const int bi2 = g / 1500, s2 = g - bi2 * 1500;
          ((u16*)out)[((size_t)((bi2 * 20 + hh) * 64 + dd)) * 1504 + s2] = src[r];
        }
      }
    }
  } else {
#pragma unroll
    for (int j = 0; j < 4; ++j) {
      const int col = n0 + wc * 64 + j * 16 + lm;
      const float bb = bias ? bias[col] : 0.0f;
      const int hh = col >> 6, dd = col & 63;
#pragma unroll
      for (int i = 0; i < 4; ++i) {
        const int row0 = m0 + wr * 64 + i * 16 + quad * 4;
#pragma unroll
        for (int r = 0; r < 4; ++r) {
          const int row = row0 + r;
          if (row < M) {
            const float v = (acc[i][j][r] + bb) * scale;
            if (MODE == 0) {
              out[(size_t)row * 1280 + col] = (OT)v;
            } else {
              const int bidx = row / 1500, s = row - bidx * 1500;
              out[((size_t)(bidx * 20 + hh) * 1500 + s) * 64 + dd] = (OT)f2bf(v);
            }
          }
        }
      }
    }
  }
}

__global__ __launch_bounds__(512, 2) void qkv_kernel(const u16* __restrict__ hs,
    const u16* __restrict__ Wq, const float* __restrict__ bq, const u16* __restrict__ Wk,
    const u16* __restrict__ Wv, const float* __restrict__ bv,
    u16* __restrict__ q_ws, u16* __restrict__ k_ws, u16* __restrict__ vt_ws, int M) {
  __shared__ __align__(16) u16 lds[3 * 24576];  // 144KB: 3-stage pipeline
  const int n = blockIdx.x;                     // grid = 720 (8 XCD * 90)
  const int xcd = n & 7, j = n >> 3;            // j in [0,90)
  const int x = xcd * 3 + (j % 3);              // [0,24)
  const int yz = j / 3;                         // [0,30)
  const int y = yz % 10, z = yz / 10;
  const int m0 = x * 256, n0 = y * 128;
  if (z == 0)
    gemm256<1, u16>(hs, Wq, bq, q_ws, 0.18033688f, M, lds, m0, n0);  // 0.125*log2(e)
  else if (z == 1)
    gemm256<1, u16>(hs, Wk, nullptr, k_ws, 1.0f, M, lds, m0, n0);
  else
    gemm256<2, u16>(hs, Wv, bv, vt_ws, 1.0f, M, lds, m0, n0);
}

__global__ __launch_bounds__(512, 2) void out_kernel(const u16* __restrict__ attn,
    const u16* __restrict__ Wo, const float* __restrict__ bo, float* __restrict__ out, int M) {
  __shared__ __align__(16) u16 lds[3 * 24576];
  const int n = blockIdx.x;                     // grid = 240 (8 XCD * 30)
  const int xcd = n & 7, j = n >> 3;            // j in [0,30)
  const int x = xcd * 3 + (j % 3);              // [0,24)
  const int y = j / 3;                          // [0,10)
  gemm256<0, float>(attn, Wo, bo, out, 1.0f, M, lds, x * 256, y * 128);
}

// ---------------- Flash attention: 3-stage counted-vmcnt K/V pipeline ----------------
// (unchanged from r7 — verified win)
__global__ __launch_bounds__(256, 3) void attn_kernel(const u16* __restrict__ Qm,
    const u16* __restrict__ Km, const u16* __restrict__ Vtm, u16* __restrict__ Out) {
  const int n = blockIdx.x;                     // grid = 960 (8 XCD * 120)
  const int xcd = n & 7, j = n >> 3;            // j in [0,120)
  const int bh = xcd * 10 + (j % 10);           // 10 bh per XCD (bijective)
  const int qt = j / 10;                        // [0,12)
  const int b = bh / 20, h = bh % 20;
  const int tid = threadIdx.x, wid = tid >> 6, lane = tid & 63;
  const int lm = lane & 15, quad = lane >> 4;

  __shared__ __align__(16) u16 lds[3 * 8192];   // 48KB: 3 stages x {K 4096, V 4096} u16

  const u16* Qb = Qm + (size_t)bh * (1500 * 64);
  const u16* Kb = Km + (size_t)bh * (1500 * 64);
  const u16* Vb = Vtm + (size_t)bh * (64 * 1504);

  bf16x8 qf[2][2];
#pragma unroll
  for (int g = 0; g < 2; ++g) {
    int qrow = qt * 128 + wid * 32 + g * 16 + lm;
    if (qrow > 1499) qrow = 1499;                 // dup rows masked at store
    qf[g][0] = *(const bf16x8*)(Qb + (size_t)qrow * 64 + quad * 8);
    qf[g][1] = *(const bf16x8*)(Qb + (size_t)qrow * 64 + 32 + quad * 8);
  }

  const int rr = tid >> 3, cc = tid & 7;
  const int s0 = (cc ^ (rr & 7)) * 8;             // (rr+32)&7 == rr&7

  auto stage = [&](int kt, int bi) {
    int kr0 = kt + rr;      if (kr0 > 1499) kr0 = 1499;
    int kr1 = kt + rr + 32; if (kr1 > 1499) kr1 = 1499;
    int vcol = kt + s0;     if (vcol > 1496) vcol = 1496;   // keep V reads in-bounds/finite
    u16* lk = lds + bi * 8192 + wid * 512;
    u16* lv = lk + 4096;
    glds16(Kb + (size_t)kr0 * 64 + s0, lk);
    glds16(Kb + (size_t)kr1 * 64 + s0, lk + 2048);
    glds16(Vb + (size_t)rr * 1504 + vcol, lv);
    glds16(Vb + (size_t)(rr + 32) * 1504 + vcol, lv + 2048);
  };

  stage(0, 0);
  stage(64, 1);
  asm volatile("s_waitcnt vmcnt(4)" ::: "memory");
  __builtin_amdgcn_s_barrier();

  float m_s[2] = {-1e30f, -1e30f};
  float l_s[2] = {0.f, 0.f};
  f32x4 o_acc[2][4] = {};

  int bsel = 0;
  for (int it = 0; it < 24; ++it) {
    const u16* Kc = lds + bsel * 8192;
    const u16* Vc = Kc + 4096;
    if (it + 2 < 24) stage((it + 2) * 64, bsel >= 1 ? bsel - 1 : 2);  // (bsel+2)%3

    // S^T = K Q^T : st[g][t] lane holds q-row lm, kpos = t*16 + quad*4 + r
    f32x4 st[2][4] = {};
    __builtin_amdgcn_s_setprio(1);
#pragma unroll
    for (int kk = 0; kk < 2; ++kk) {
#pragma unroll
      for (int t = 0; t < 4; ++t) {
        const bf16x8 kf = *(const bf16x8*)(Kc + (t * 16 + lm) * 64 + (((kk * 4 + quad) ^ (lm & 7)) * 8));
        st[0][t] = __builtin_amdgcn_mfma_f32_16x16x32_bf16(kf, qf[0][kk], st[0][t], 0, 0, 0);
        st[1][t] = __builtin_amdgcn_mfma_f32_16x16x32_bf16(kf, qf[1][kk], st[1][t], 0, 0, 0);
      }
    }
    __builtin_amdgcn_s_setprio(0);
    if (it == 23) {                               // ragged tile: kpos = 1472 + t*16+quad*4+r
#pragma unroll
      for (int t = 0; t < 4; ++t)
#pragma unroll
        for (int r = 0; r < 4; ++r)
          if (t * 16 + quad * 4 + r >= 28) { st[0][t][r] = -1e30f; st[1][t][r] = -1e30f; }
    }

    bf16x8 pf[2][2];
#pragma unroll
    for (int g = 0; g < 2; ++g) {
      float a0 = fmaxf(fmaxf(st[g][0][0], st[g][0][1]), fmaxf(st[g][0][2], st[g][0][3]));
      float a1 = fmaxf(fmaxf(st[g][1][0], st[g][1][1]), fmaxf(st[g][1][2], st[g][1][3]));
      float a2 = fmaxf(fmaxf(st[g][2][0], st[g][2][1]), fmaxf(st[g][2][2], st[g][2][3]));
      float a3 = fmaxf(fmaxf(st[g][3][0], st[g][3][1]), fmaxf(st[g][3][2], st[g][3][3]));
      float rm = xquad_max(fmaxf(fmaxf(a0, a1), fmaxf(a2, a3)));

      // T13 defer-max (THR=8, exp2 domain -> P<=256). Wave-uniform branch.
      if (!__all(rm - m_s[g] <= 8.0f)) {
        const float mn = fmaxf(m_s[g], rm);
        const float al = fexp2(m_s[g] - mn);      // first iter: fexp2(-1e30) = 0
        m_s[g] = mn;
        l_s[g] *= al;
#pragma unroll
        for (int r = 0; r < 4; ++r) {
          const float ao = __shfl(al, quad * 4 + r);
#pragma unroll
          for (int t = 0; t < 4; ++t) o_acc[g][t][r] *= ao;
        }
      }
      const float mn = m_s[g];

      float rs = 0.f;
      unsigned A[4], B[4];
#pragma unroll
      for (int t = 0; t < 4; ++t) {
        const float p0 = fexp2(st[g][t][0] - mn);
        const float p1 = fexp2(st[g][t][1] - mn);
        const float p2 = fexp2(st[g][t][2] - mn);
        const float p3 = fexp2(st[g][t][3] - mn);
        rs += (p0 + p1) + (p2 + p3);
        A[t] = cvt_pk_bf16(p0, p1);
        B[t] = cvt_pk_bf16(p2, p3);
      }
      l_s[g] += xquad_sum(rs);                    // off the PV critical path

#pragma unroll
      for (int kk = 0; kk < 2; ++kk) {
        unsigned x0 = A[2 * kk], x1 = A[2 * kk + 1];
        quad_swap(x0, x1);                        // -> dwords 0 (k+0,1) and 2 (k+4,5)
        unsigned y0 = B[2 * kk], y1 = B[2 * kk + 1];
        quad_swap(y0, y1);                        // -> dwords 1 (k+2,3) and 3 (k+6,7)
        u32x4 w; w[0] = x0; w[1] = y0; w[2] = x1; w[3] = y1;
        pf[g][kk] = __builtin_bit_cast(bf16x8, w);
      }
    }

    // O += P V
    __builtin_amdgcn_s_setprio(1);
#pragma unroll
    for (int kk = 0; kk < 2; ++kk) {
#pragma unroll
      for (int t = 0; t < 4; ++t) {
        const bf16x8 vf = *(const bf16x8*)(Vc + (t * 16 + lm) * 64 + (((kk * 4 + quad) ^ (lm & 7)) * 8));
        o_acc[0][t] = __builtin_amdgcn_mfma_f32_16x16x32_bf16(pf[0][kk], vf, o_acc[0][t], 0, 0, 0);
        o_acc[1][t] = __builtin_amdgcn_mfma_f32_16x16x32_bf16(pf[1][kk], vf, o_acc[1][t], 0, 0, 0);
      }
    }
    __builtin_amdgcn_s_setprio(0);

    if (it + 1 < 24) {                            // boundary: tile it+1 must be resident
      if (it + 2 < 24) asm volatile("s_waitcnt vmcnt(4)" ::: "memory");
      else             asm volatile("s_waitcnt vmcnt(0)" ::: "memory");
      __builtin_amdgcn_s_barrier();
    }
    bsel = bsel == 2 ? 0 : bsel + 1;
  }

#pragma unroll
  for (int g = 0; g < 2; ++g)
#pragma unroll
    for (int r = 0; r < 4; ++r) {
      const float lr = __shfl(l_s[g], quad * 4 + r);
      const float inv = 1.0f / lr;
      const int qg = qt * 128 + wid * 32 + g * 16 + quad * 4 + r;
      if (qg < 1500) {
#pragma unroll
        for (int t = 0; t < 4; ++t)
          Out[((size_t)(b * 1500 + qg)) * 1280 + h * 64 + t * 16 + lm] =
              f2bf(o_acc[g][t][r] * inv);
      }
    }
}

extern "C" void kernel_launch(void* const* d_in, const int* in_sizes, int n_in,
                              void* d_out, int out_size, void* d_ws, size_t ws_size,
                              hipStream_t stream) {
  const float* hs = (const float*)d_in[0];
  const float* Wq = (const float*)d_in[2];
  const float* bq = (const float*)d_in[3];
  const float* Wk = (const float*)d_in[4];
  const float* Wv = (const float*)d_in[5];
  const float* bv = (const float*)d_in[6];
  const float* Wo = (const float*)d_in[7];
  const float* bo = (const float*)d_in[8];

  u16* cvt     = (u16*)d_ws;
  u16* hs_bf   = cvt;                          // [6000,1280]
  u16* Wq_bf   = cvt + 7680000;
  u16* Wk_bf   = cvt + 9318400;
  u16* Wv_bf   = cvt + 10956800;
  u16* Wo_bf   = cvt + 12595200;
  u16* q_ws    = cvt + 14233600;               // [4,20,1500,64]
  u16* k_ws    = q_ws + 7680000;
  u16* vt_ws   = k_ws + 7680000;               // [4,20,64,1504] (+64 pad)
  u16* attn_ws = vt_ws + 7700480 + 64;         // [6000,1280]
  const int M = 6000;

  hipLaunchKernelGGL(cvt_kernel, dim3(2048), dim3(256), 0, stream,
                     (const float4*)hs, (const float4*)Wq, (const float4*)Wk,
                     (const float4*)Wv, (const float4*)Wo, cvt);
  hipLaunchKernelGGL(qkv_kernel, dim3(720), dim3(512), 0, stream,
                     hs_bf, Wq_bf, bq, Wk_bf, Wv_bf, bv, q_ws, k_ws, vt_ws, M);
  hipLaunchKernelGGL(attn_kernel, dim3(960), dim3(256), 0, stream,
                     q_ws, k_ws, vt_ws, attn_ws);
  hipLaunchKernelGGL(out_kernel, dim3(240), dim3(512), 0, stream,
                     attn_ws, Wo_bf, bo, (float*)d_out, M);
}